// Round 6
// baseline (949.467 us; speedup 1.0000x reference)
//
#include <hip/hip_runtime.h>

// ---- problem geometry ----
#define NTIPS 512
#define DIM   510                     // internal nodes = ntips - 2
#define TOTAL 1022
#define BS    64
#define ITERS 50

// ---- 16-feat slabs, single-buffered LDS (R5-validated inner loop) ----
#define NSLAB2 32
#define NWG2   (BS * NSLAB2)          // 2048 workgroups = capacity @ 8 WG/CU
#define ROWEL2 16                     // u16 per row-slab (32 B)
#define XSEC2  (DIM * ROWEL2)         // 8160 u16
#define ONE2   XSEC2                  // 16 one-hot const rows
#define ZROW2  (XSEC2 + 16 * ROWEL2)  // all-zero const row
#define BSTR2  (XSEC2 + 17 * ROWEL2)  // 8432 u16 = 16864 B single buffer
#define WGB2   (DIM * ROWEL2 * 2)     // bytes per WG region in a slot = 16320
#define XB2    ((size_t)BS * DIM * NTIPS)   // u16 elems per snapshot slot
#define SLOTB2 (XB2 * 2)              // 33.4 MB per slot
#define NPART2 ((size_t)ITERS * NWG2)

typedef unsigned short u16;
typedef unsigned int   u32;
typedef float f32x2 __attribute__((ext_vector_type(2)));

// bf16 RNE helpers (validated chain)
__device__ __forceinline__ u16 f2bf(float x) {
    u32 u = __float_as_uint(x);
    return (u16)((u + 0x7FFFu + ((u >> 16) & 1u)) >> 16);
}
__device__ __forceinline__ float bf2f(u16 h) { return __uint_as_float(((u32)h) << 16); }
__device__ __forceinline__ float bflo(u32 p) { return __uint_as_float(p << 16); }
__device__ __forceinline__ float bfhi(u32 p) { return __uint_as_float(p & 0xFFFF0000u); }
__device__ __forceinline__ f32x2 unpk(u32 p) {
    f32x2 r; r.x = bflo(p); r.y = bfhi(p); return r;
}

#if defined(__has_builtin)
#  if __has_builtin(__builtin_amdgcn_cvt_pk_bf16_f32)
#    define HAVE_PKBF 1
#  endif
#endif
#ifdef HAVE_PKBF
typedef __bf16 bf16x2 __attribute__((ext_vector_type(2)));
__device__ __forceinline__ u32 pkbf(float a, float b) {   // lo=a, hi=b, RNE
    bf16x2 r = __builtin_amdgcn_cvt_pk_bf16_f32(a, b);
    return __builtin_bit_cast(u32, r);
}
#else
__device__ __forceinline__ u32 pkbf(float a, float b) {
    return (u32)f2bf(a) | ((u32)f2bf(b) << 16);
}
#endif

// correctly-rounded f32 /3 (Markstein mul+2fma) — R2..R5-validated
__device__ __forceinline__ f32x2 div3v(f32x2 x) {
    const float C = 0x1.555556p-2f;               // RN(1/3)
    f32x2 q0, r, q;
    q0.x = x.x * C;             q0.y = x.y * C;
    r.x = fmaf(-3.f, q0.x, x.x); r.y = fmaf(-3.f, q0.y, x.y);
    q.x = fmaf(r.x, C, q0.x);    q.y = fmaf(r.y, C, q0.y);
    return q;
}

// one packed pair with delta accumulation — R5-validated
__device__ __forceinline__ u32 stepElem(u32 a0, u32 a1, u32 a2, u32 own,
                                        float& dacc) {
    const f32x2 a = (unpk(a0) + unpk(a1)) + unpk(a2);
    const f32x2 q = div3v(a);
    const u32 nv = pkbf(q.x, q.y);
    const f32x2 n = unpk(nv), o = unpk(own);
    const u32 dd = pkbf(n.x - o.x, n.y - o.y);
    dacc += fabsf(bflo(dd));
    dacc += fabsf(bfhi(dd));
    return nv;
}
// no-delta variant (phaseC re-run: partials not needed)
__device__ __forceinline__ u32 stepElemND(u32 a0, u32 a1, u32 a2) {
    const f32x2 a = (unpk(a0) + unpk(a1)) + unpk(a2);
    const f32x2 q = div3v(a);
    return pkbf(q.x, q.y);
}

// gather offsets (bytes, LDS-relative), 16-feat slab
__device__ __forceinline__ void make_offsets2(const int* __restrict__ edge,
        int b, int sl, int rg, int lbyte, int nr, u32 offB[4][3]) {
    #pragma unroll
    for (int k = 0; k < 4; ++k) if (k < nr) {
        const int i = rg + (k << 7);
        const int* ep = edge + ((size_t)b * TOTAL + NTIPS + i) * 3;
        #pragma unroll
        for (int t = 0; t < 3; ++t) {
            const int e = ep[t];
            u32 off;
            if (e >= NTIPS)          off = (u32)((e - NTIPS) * ROWEL2);
            else if ((e >> 4) == sl) off = (u32)(ONE2 + (e & 15) * ROWEL2);
            else                     off = (u32)ZROW2;
            offB[k][t] = off * 2u + (u32)lbyte;
        }
    }
}

// schedule: chunks q=1..8, widths {4,4,4,8,8,8,8,6}, snapshot -> slot q&1
// resolve S -> (T steps to re-run, source slot, from-X0?)
__device__ __forceinline__ void resolveS(int S, int& T, int& slot, int& fromX0) {
    const int sBegs[8] = {1, 5, 9, 13, 21, 29, 37, 45};
    const int sEnds[8] = {4, 8, 12, 20, 28, 36, 44, 50};
    int q = 0;
    #pragma unroll
    for (int i = 0; i < 8; ++i) if (S >= sBegs[i]) q = i;
    const int qq = q + 1;
    if (S == sEnds[q])      { T = 0; slot = qq & 1;       fromX0 = 0; }
    else if (qq == 1)       { T = S; slot = 0;            fromX0 = 1; }
    else                    { T = S - sBegs[q] + 1; slot = (qq - 1) & 1; fromX0 = 0; }
}

// ---------------------------------------------------------------------------
// chunk2: W steps entirely in LDS (single buffer, read-phase/write-phase),
// NO per-step snapshots (R3 showed 33 MB/step writes == the whole step time).
// One snapshot at chunk end -> slot q&1. partials per step (plain stores,
// visible to findS via kernel boundary — no fences, R1/R2 lesson).
// ---------------------------------------------------------------------------
template<int W>
__global__ __launch_bounds__(256, 8) void chunk2_kernel(
        const int* __restrict__ edge, float* __restrict__ partials,
        const int* __restrict__ ctrl, u16* __restrict__ slots,
        int q, int sBeg) {
    if (q >= 2 && ctrl[2] != 0) return;          // converged: skip

    __shared__ u16 X[BSTR2];
    __shared__ float redL[4];

    const int wg = blockIdx.x, b = wg >> 5, sl = wg & 31;
    const int tid = threadIdx.x;
    const int rg = tid >> 1;                 // row group 0..127
    const int h  = tid & 1;                  // feature half (8 feats = 16 B)
    const int lbyte = h << 4;
    const int nr = (rg < 126) ? 4 : 3;       // rows rg+128k < 510
    char* Xc = reinterpret_cast<char*>(X);
    const u32 r0b = (u32)(rg * 32 + lbyte);  // own-row LDS byte base (+k<<12)

    u32 offB[4][3];
    make_offsets2(edge, b, sl, rg, lbyte, nr, offB);

    u32 rowByte[4];                          // slab-major slot offsets
    #pragma unroll
    for (int k = 0; k < 4; ++k)
        rowByte[k] = (u32)wg * (u32)WGB2 + (u32)((rg + (k << 7)) * 32) + (u32)lbyte;

    if (q == 1) {
        for (int j = tid; j < XSEC2 / 2; j += 256)
            reinterpret_cast<u32*>(X)[j] = 0x3B003B00u;   // X0 = bf16(1/512)
    } else {
        const char* src0 = reinterpret_cast<const char*>(slots)
                         + (size_t)((q - 1) & 1) * SLOTB2;
        #pragma unroll
        for (int k = 0; k < 4; ++k) if (k < nr)
            *reinterpret_cast<uint4*>(Xc + r0b + (k << 12)) =
                *reinterpret_cast<const uint4*>(src0 + rowByte[k]);
    }
    for (int j = tid; j < 17 * ROWEL2; j += 256) {
        const int row = j >> 4, col = j & 15;
        X[ONE2 + j] = (row == col) ? (u16)0x3F80 : (u16)0;
    }
    __syncthreads();

    uint4 nvP[4];
    #pragma unroll
    for (int u = 0; u < W; ++u) {
        const int s = sBeg + u;
        float dacc = 0.f;
        // phase A: all reads (own + 3 gathers) -> nv regs + delta
        #pragma unroll
        for (int k = 0; k < 4; ++k) if (k < nr) {
            const uint4 own = *reinterpret_cast<const uint4*>(Xc + r0b + (k << 12));
            const uint4 g0 = *reinterpret_cast<const uint4*>(Xc + offB[k][0]);
            const uint4 g1 = *reinterpret_cast<const uint4*>(Xc + offB[k][1]);
            const uint4 g2 = *reinterpret_cast<const uint4*>(Xc + offB[k][2]);
            uint4 nv;
            nv.x = stepElem(g0.x, g1.x, g2.x, own.x, dacc);
            nv.y = stepElem(g0.y, g1.y, g2.y, own.y, dacc);
            nv.z = stepElem(g0.z, g1.z, g2.z, own.z, dacc);
            nv.w = stepElem(g0.w, g1.w, g2.w, own.w, dacc);
            nvP[k] = nv;
        }
        #pragma unroll
        for (int off = 32; off > 0; off >>= 1) dacc += __shfl_down(dacc, off);
        if ((tid & 63) == 0) redL[tid >> 6] = dacc;
        __syncthreads();                      // reads done + redL visible
        if (tid == 0) {
            const float dtot = ((redL[0] + redL[1]) + redL[2]) + redL[3];
            partials[(size_t)(s - 1) * NWG2 + wg] = dtot;
        }
        if (u < W - 1) {                      // phase B: publish to LDS
            #pragma unroll
            for (int k = 0; k < 4; ++k) if (k < nr)
                *reinterpret_cast<uint4*>(Xc + r0b + (k << 12)) = nvP[k];
            __syncthreads();
        }
    }

    // chunk-end snapshot (coalesced slab-major), from regs
    char* slotC = reinterpret_cast<char*>(slots) + (size_t)(q & 1) * SLOTB2;
    #pragma unroll
    for (int k = 0; k < 4; ++k) if (k < nr)
        *reinterpret_cast<uint4*>(slotC + rowByte[k]) = nvP[k];
}

// ---------------------------------------------------------------------------
// findS: separate 1-WG dispatch (kernel boundary = visibility; no fences).
// EXACT validated decision procedure; partials layout [s][wg], wg = b*32+sl.
// ---------------------------------------------------------------------------
__global__ void findS2_kernel(const float* __restrict__ partials,
                              int* __restrict__ ctrl, int smax) {
    if (ctrl[2] != 0) return;
    const int lane = threadIdx.x;                // 64 lanes = trees
    const float tol_bf = bf2f(f2bf(1e-5f));
    int S = -1;
    for (int s = 1; s <= smax; ++s) {
        const float* p = partials + (size_t)(s - 1) * NWG2 + (lane << 5);
        float t = 0.f;
        #pragma unroll
        for (int k = 0; k < NSLAB2; ++k) t += p[k];
        const float lnorm = bf2f(f2bf(t / 261120.0f));
        if (__ballot(lnorm > tol_bf) == 0ULL) { S = s; break; }
    }
    if (S < 0 && smax == ITERS) S = ITERS;       // cap at MAX_ITERS
    if (lane == 0 && S > 0) { ctrl[0] = S; ctrl[2] = 1; }
}

// ---------------------------------------------------------------------------
// copyfinal2 (fallback only, slots in d_out): copy resolved base slot -> ws.
// ---------------------------------------------------------------------------
__global__ __launch_bounds__(256) void copyfinal2_kernel(
        const int* __restrict__ ctrl, const u16* __restrict__ slots,
        u16* __restrict__ dst) {
    int T, slot, fromX0;
    resolveS(ctrl[0], T, slot, fromX0);
    if (fromX0) return;
    const uint4* src = reinterpret_cast<const uint4*>(slots + (size_t)slot * XB2);
    uint4* d = reinterpret_cast<uint4*>(dst);
    const size_t n = XB2 / 8;
    for (size_t i = (size_t)blockIdx.x * 256 + threadIdx.x; i < n;
         i += (size_t)gridDim.x * 256)
        d[i] = src[i];
}

// ---------------------------------------------------------------------------
// phaseC2: resume from resolved snapshot, run T (<=7) steps, write fp32
// output directly (fused convert; 64-B sector-aligned stores).
// ring!=0: s0 = 2-slot ring base; else s0 = single prepared state.
// ---------------------------------------------------------------------------
__global__ __launch_bounds__(256, 8) void phaseC2_kernel(
        const int* __restrict__ edge, const int* __restrict__ ctrl,
        const u16* __restrict__ s0, int ring, float* __restrict__ out) {
    __shared__ u16 X[BSTR2];

    const int S = ctrl[0];
    int T, slot, fromX0;
    resolveS(S, T, slot, fromX0);

    const int wg = blockIdx.x, b = wg >> 5, sl = wg & 31;
    const int tid = threadIdx.x;
    const int rg = tid >> 1, h = tid & 1;
    const int lbyte = h << 4;
    const int nr = (rg < 126) ? 4 : 3;
    char* Xc = reinterpret_cast<char*>(X);
    const u32 r0b = (u32)(rg * 32 + lbyte);

    u32 offB[4][3];
    make_offsets2(edge, b, sl, rg, lbyte, nr, offB);

    if (fromX0) {
        for (int j = tid; j < XSEC2 / 2; j += 256)
            reinterpret_cast<u32*>(X)[j] = 0x3B003B00u;
    } else {
        const char* src = reinterpret_cast<const char*>(s0)
                        + (ring ? (size_t)slot * SLOTB2 : (size_t)0);
        const u32 wb = (u32)wg * (u32)WGB2;
        #pragma unroll
        for (int k = 0; k < 4; ++k) if (k < nr) {
            const u32 rb = wb + (u32)((rg + (k << 7)) * 32) + (u32)lbyte;
            *reinterpret_cast<uint4*>(Xc + r0b + (k << 12)) =
                *reinterpret_cast<const uint4*>(src + rb);
        }
    }
    for (int j = tid; j < 17 * ROWEL2; j += 256) {
        const int row = j >> 4, col = j & 15;
        X[ONE2 + j] = (row == col) ? (u16)0x3F80 : (u16)0;
    }
    __syncthreads();

    for (int t = 1; t <= T; ++t) {
        uint4 nvP[4];
        #pragma unroll
        for (int k = 0; k < 4; ++k) if (k < nr) {
            const uint4 g0 = *reinterpret_cast<const uint4*>(Xc + offB[k][0]);
            const uint4 g1 = *reinterpret_cast<const uint4*>(Xc + offB[k][1]);
            const uint4 g2 = *reinterpret_cast<const uint4*>(Xc + offB[k][2]);
            uint4 nv;
            nv.x = stepElemND(g0.x, g1.x, g2.x);
            nv.y = stepElemND(g0.y, g1.y, g2.y);
            nv.z = stepElemND(g0.z, g1.z, g2.z);
            nv.w = stepElemND(g0.w, g1.w, g2.w);
            nvP[k] = nv;
        }
        __syncthreads();                      // all reads done
        #pragma unroll
        for (int k = 0; k < 4; ++k) if (k < nr)
            *reinterpret_cast<uint4*>(Xc + r0b + (k << 12)) = nvP[k];
        __syncthreads();                      // X_{c+t} published
    }

    // fused output: this WG owns feature columns [sl*16, sl*16+16) of tree b.
    // identity rows (0..511)
    float* obase = out + (size_t)b * TOTAL * NTIPS + sl * 16;
    for (int j = tid; j < NTIPS * 4; j += 256) {
        const int r = j >> 2, c4 = (j & 3) << 2;
        const int fc = sl * 16 + c4;
        float4 v;
        v.x = (r == fc + 0) ? 1.f : 0.f;
        v.y = (r == fc + 1) ? 1.f : 0.f;
        v.z = (r == fc + 2) ? 1.f : 0.f;
        v.w = (r == fc + 3) ? 1.f : 0.f;
        *reinterpret_cast<float4*>(obase + (size_t)r * NTIPS + c4) = v;
    }
    // X rows (512..1021) from LDS
    float* xbase = obase + (size_t)NTIPS * NTIPS;
    for (int j = tid; j < DIM * 4; j += 256) {
        const int r = j >> 2, c4 = (j & 3) << 2;
        const ushort4 a = *reinterpret_cast<const ushort4*>(&X[r * ROWEL2 + c4]);
        float4 v;
        v.x = bf2f(a.x); v.y = bf2f(a.y); v.z = bf2f(a.z); v.w = bf2f(a.w);
        *reinterpret_cast<float4*>(xbase + (size_t)r * NTIPS + c4) = v;
    }
}

extern "C" void kernel_launch(void* const* d_in, const int* in_sizes, int n_in,
                              void* d_out, int out_size, void* d_ws, size_t ws_size,
                              hipStream_t stream) {
    const int* edge = (const int*)d_in[1];       // (BS, TOTAL, 3) int32
    float* out = (float*)d_out;
    const size_t partB = NPART2 * sizeof(float);

    static const int sBegs[8] = {1, 5, 9, 13, 21, 29, 37, 45};
    static const int Ws[8]    = {4, 4, 4, 8, 8, 8, 8, 6};

    if (ws_size >= 2 * SLOTB2 + partB + 256) {
        // ---- primary: 2-slot ring in ws ----
        u16*   slots    = (u16*)d_ws;
        float* partials = (float*)((char*)d_ws + 2 * SLOTB2);
        int*   ctrl     = (int*)((char*)partials + partB);
        hipMemsetAsync(ctrl, 0, 4 * sizeof(int), stream);
        for (int i = 0; i < 8; ++i) {
            const int q = i + 1, sb = sBegs[i];
            if (Ws[i] == 4)
                chunk2_kernel<4><<<NWG2, 256, 0, stream>>>(edge, partials, ctrl,
                                                           slots, q, sb);
            else if (Ws[i] == 8)
                chunk2_kernel<8><<<NWG2, 256, 0, stream>>>(edge, partials, ctrl,
                                                           slots, q, sb);
            else
                chunk2_kernel<6><<<NWG2, 256, 0, stream>>>(edge, partials, ctrl,
                                                           slots, q, sb);
            findS2_kernel<<<1, 64, 0, stream>>>(partials, ctrl, sb + Ws[i] - 1);
        }
        phaseC2_kernel<<<NWG2, 256, 0, stream>>>(edge, ctrl, slots, 1, out);
    } else {
        // ---- fallback: 2-slot ring in d_out, base copied to ws ----
        u16*   slots    = (u16*)d_out;
        u16*   finalX   = (u16*)d_ws;
        float* partials = (float*)((char*)d_ws + SLOTB2);
        int*   ctrl     = (int*)((char*)partials + partB);
        hipMemsetAsync(ctrl, 0, 4 * sizeof(int), stream);
        for (int i = 0; i < 8; ++i) {
            const int q = i + 1, sb = sBegs[i];
            if (Ws[i] == 4)
                chunk2_kernel<4><<<NWG2, 256, 0, stream>>>(edge, partials, ctrl,
                                                           slots, q, sb);
            else if (Ws[i] == 8)
                chunk2_kernel<8><<<NWG2, 256, 0, stream>>>(edge, partials, ctrl,
                                                           slots, q, sb);
            else
                chunk2_kernel<6><<<NWG2, 256, 0, stream>>>(edge, partials, ctrl,
                                                           slots, q, sb);
            findS2_kernel<<<1, 64, 0, stream>>>(partials, ctrl, sb + Ws[i] - 1);
        }
        copyfinal2_kernel<<<2048, 256, 0, stream>>>(ctrl, slots, finalX);
        phaseC2_kernel<<<NWG2, 256, 0, stream>>>(edge, ctrl, finalX, 0, out);
    }
}

// Round 7
// 306.166 us; speedup vs baseline: 3.1011x; 3.1011x over previous
//
#include <hip/hip_runtime.h>

// ---- problem geometry ----
#define NTIPS 512
#define DIM   510                     // internal nodes = ntips - 2
#define TOTAL 1022
#define BS    64
#define ITERS 50

// ---- chunk config: 8-feat slabs (R4-proven uint2 body), double-buffer ----
#define NSLAB 64
#define NWG   (BS * NSLAB)            // 4096 workgroups
#define NPART ((size_t)ITERS * BS * NSLAB)
#define ROWEL 8                       // u16 per row-slab (16 B)
#define XSEC   (DIM * ROWEL)          // 4080 u16
#define ONEOFF XSEC                   // 8 one-hot const rows
#define ZROW   (XSEC + 8 * ROWEL)     // all-zero const row
#define BSTRIDE (XSEC + 9 * ROWEL)    // 4152 u16 per LDS buffer
#define BUFB   (BSTRIDE * 2)          // 8304 B per buffer (2 buffers = 16.6KB)
#define WGB    (DIM * ROWEL * 2)      // 8160 B per WG region in a slot
#define XB     ((size_t)BS * DIM * NTIPS)  // u16 per snapshot slot
#define SLOTB  (XB * 2)               // 33.4 MB per slot

// ---- phaseC config: 16-feat slabs (64-B output rows), single-buffer ----
#define NSLAB2 32
#define NWG2   (BS * NSLAB2)          // 2048 workgroups
#define ROWEL2 16
#define XSEC2  (DIM * ROWEL2)         // 8160 u16
#define ONE2   XSEC2
#define ZROW2  (XSEC2 + 16 * ROWEL2)
#define BSTR2  (XSEC2 + 17 * ROWEL2)  // 8432 u16 = 16864 B

typedef unsigned short u16;
typedef unsigned int   u32;
typedef float f32x2 __attribute__((ext_vector_type(2)));

// bf16 RNE helpers (validated chain)
__device__ __forceinline__ u16 f2bf(float x) {
    u32 u = __float_as_uint(x);
    return (u16)((u + 0x7FFFu + ((u >> 16) & 1u)) >> 16);
}
__device__ __forceinline__ float bf2f(u16 h) { return __uint_as_float(((u32)h) << 16); }
__device__ __forceinline__ float bflo(u32 p) { return __uint_as_float(p << 16); }
__device__ __forceinline__ float bfhi(u32 p) { return __uint_as_float(p & 0xFFFF0000u); }
__device__ __forceinline__ f32x2 unpk(u32 p) {
    f32x2 r; r.x = bflo(p); r.y = bfhi(p); return r;
}

#if defined(__has_builtin)
#  if __has_builtin(__builtin_amdgcn_cvt_pk_bf16_f32)
#    define HAVE_PKBF 1
#  endif
#endif
#ifdef HAVE_PKBF
typedef __bf16 bf16x2 __attribute__((ext_vector_type(2)));
__device__ __forceinline__ u32 pkbf(float a, float b) {   // lo=a, hi=b, RNE
    bf16x2 r = __builtin_amdgcn_cvt_pk_bf16_f32(a, b);
    return __builtin_bit_cast(u32, r);
}
#else
__device__ __forceinline__ u32 pkbf(float a, float b) {
    return (u32)f2bf(a) | ((u32)f2bf(b) << 16);
}
#endif

// correctly-rounded f32 /3 (Markstein mul+2fma) — R2..R6-validated
__device__ __forceinline__ f32x2 div3v(f32x2 x) {
    const float C = 0x1.555556p-2f;               // RN(1/3)
    f32x2 q0, r, q;
    q0.x = x.x * C;             q0.y = x.y * C;
    r.x = fmaf(-3.f, q0.x, x.x); r.y = fmaf(-3.f, q0.y, x.y);
    q.x = fmaf(r.x, C, q0.x);    q.y = fmaf(r.y, C, q0.y);
    return q;
}
// no-delta packed-pair step (phaseC)
__device__ __forceinline__ u32 stepND(u32 a0, u32 a1, u32 a2) {
    const f32x2 a = (unpk(a0) + unpk(a1)) + unpk(a2);
    const f32x2 q = div3v(a);
    return pkbf(q.x, q.y);
}

// LDS-only barrier (R3/R4-validated): no vmcnt drain
__device__ __forceinline__ void barrier_lds_only() {
    __builtin_amdgcn_sched_barrier(0);
    asm volatile("s_waitcnt lgkmcnt(0)" ::: "memory");
    __builtin_amdgcn_s_barrier();
    __builtin_amdgcn_sched_barrier(0);
}

// schedule: chunks q=1..8, widths {4,4,4,8,8,8,8,6}, snapshot -> slot q&1
__device__ __forceinline__ void resolveS(int S, int& T, int& slot, int& fromX0) {
    const int sBegs[8] = {1, 5, 9, 13, 21, 29, 37, 45};
    const int sEnds[8] = {4, 8, 12, 20, 28, 36, 44, 50};
    int q = 0;
    #pragma unroll
    for (int i = 0; i < 8; ++i) if (S >= sBegs[i]) q = i;
    const int qq = q + 1;
    if (S == sEnds[q])      { T = 0; slot = qq & 1;       fromX0 = 0; }
    else if (qq == 1)       { T = S; slot = 0;            fromX0 = 1; }
    else                    { T = S - sBegs[q] + 1; slot = (qq - 1) & 1; fromX0 = 0; }
}

// gather offsets for 8-feat slabs (BYTE units, buffer-relative) — R4-proven
__device__ __forceinline__ void make_offsets8(const int* __restrict__ edge,
        int b, int sl, int rg, int lbyte, int nr, u32 offB[4][3]) {
    #pragma unroll
    for (int k = 0; k < 4; ++k) if (k < nr) {
        const int i = rg + 128 * k;
        const int* ep = edge + ((size_t)b * TOTAL + NTIPS + i) * 3;
        #pragma unroll
        for (int t = 0; t < 3; ++t) {
            const int e = ep[t];
            u32 off;
            if (e >= NTIPS)          off = (u32)((e - NTIPS) * ROWEL);
            else if ((e >> 3) == sl) off = (u32)(ONEOFF + (e & 7) * ROWEL);
            else                     off = (u32)ZROW;
            offB[k][t] = off * 2u + (u32)lbyte;
        }
    }
}

__device__ __forceinline__ void init_const_rows8(u16* X, int tid) {
    for (int j = tid; j < 9 * ROWEL; j += 256) {
        const int row = j >> 3, col = j & 7;
        const u16 v = (row == col) ? (u16)0x3F80 : (u16)0;  // row 8 = zeros
        X[ONEOFF + j] = v;
        X[BSTRIDE + ONEOFF + j] = v;
    }
}

// ---------------------------------------------------------------------------
// chunk3: R4's proven double-buffer uint2 body, MINUS per-step snapshots
// (R6's correct idea), PLUS one chunk-end snapshot -> slot q&1.
// uint2 granularity keeps VGPR ~50 under the (256,8) 64-reg cap — R6's
// uint4 variant spilled to scratch (560 MB phantom FETCH).
// ---------------------------------------------------------------------------
template<int W>
__global__ __launch_bounds__(256, 8) void chunk3_kernel(
        const int* __restrict__ edge, float* __restrict__ partials,
        const int* __restrict__ ctrl, u16* __restrict__ slots, int q, int sBeg) {
    if (q >= 2 && ctrl[2] != 0) return;          // converged: skip

    __shared__ u16 X[2 * BSTRIDE];
    __shared__ float redL[2][4];

    const int wg = blockIdx.x, b = wg >> 6, sl = wg & 63;
    const int tid = threadIdx.x, rg = tid >> 1;
    const int lbyte = (tid & 1) << 3;
    const int nr = (rg < 126) ? 4 : 3;
    char* Xc = reinterpret_cast<char*>(X);
    const u32 r0b = (u32)(rg * 16 + lbyte);

    u32 offB[4][3];
    make_offsets8(edge, b, sl, rg, lbyte, nr, offB);

    u32 rowByte[4];                          // slab-major slot offsets
    #pragma unroll
    for (int k = 0; k < 4; ++k)
        rowByte[k] = (u32)wg * (u32)WGB + (u32)((rg + 128 * k) * 16) + (u32)lbyte;

    if (q == 1) {
        for (int j = tid; j < XSEC / 2; j += 256)
            reinterpret_cast<u32*>(X)[j] = 0x3B003B00u;   // X0 = bf16(1/512)
    } else {
        const char* src0 = reinterpret_cast<const char*>(slots)
                         + (size_t)((q - 1) & 1) * SLOTB;
        #pragma unroll
        for (int k = 0; k < 4; ++k) if (k < nr)
            *reinterpret_cast<uint2*>(Xc + r0b + (k << 11)) =
                *reinterpret_cast<const uint2*>(src0 + rowByte[k]);
    }
    init_const_rows8(X, tid);

    f32x2 old01[4], old23[4];
    #pragma unroll
    for (int k = 0; k < 4; ++k) if (k < nr) {
        const uint2 ov = *reinterpret_cast<const uint2*>(Xc + r0b + (k << 11));
        old01[k] = unpk(ov.x); old23[k] = unpk(ov.y);
    }
    __syncthreads();

    #pragma unroll
    for (int u = 0; u < W; ++u) {
        const int s = sBeg + u;
        const int srcB = (u & 1) ? BUFB : 0;     // compile-time after unroll
        const int dstB = ((u + 1) & 1) ? BUFB : 0;
        float dacc = 0.f;
        #pragma unroll
        for (int k = 0; k < 4; ++k) if (k < nr) {
            const uint2 g0 = *reinterpret_cast<const uint2*>(Xc + offB[k][0] + srcB);
            const uint2 g1 = *reinterpret_cast<const uint2*>(Xc + offB[k][1] + srcB);
            const uint2 g2 = *reinterpret_cast<const uint2*>(Xc + offB[k][2] + srcB);
            const f32x2 a01 = (unpk(g0.x) + unpk(g1.x)) + unpk(g2.x);
            const f32x2 a23 = (unpk(g0.y) + unpk(g1.y)) + unpk(g2.y);
            const f32x2 q01 = div3v(a01), q23 = div3v(a23);
            uint2 nv;
            nv.x = pkbf(q01.x, q01.y);
            nv.y = pkbf(q23.x, q23.y);
            *reinterpret_cast<uint2*>(Xc + r0b + ((k << 11) + dstB)) = nv;
            const f32x2 n01 = unpk(nv.x), n23 = unpk(nv.y);
            const f32x2 d01v = n01 - old01[k];
            const f32x2 d23v = n23 - old23[k];
            const u32 d01 = pkbf(d01v.x, d01v.y);
            const u32 d23 = pkbf(d23v.x, d23v.y);
            dacc += fabsf(bflo(d01));
            dacc += fabsf(bfhi(d01));
            dacc += fabsf(bflo(d23));
            dacc += fabsf(bfhi(d23));
            old01[k] = n01; old23[k] = n23;
        }
        #pragma unroll
        for (int off = 32; off > 0; off >>= 1) dacc += __shfl_down(dacc, off);
        if ((tid & 63) == 0) redL[u & 1][tid >> 6] = dacc;
        barrier_lds_only();                      // LDS wait only, no vm drain
        if (tid == 0) {
            const float dtot = ((redL[u & 1][0] + redL[u & 1][1])
                                + redL[u & 1][2]) + redL[u & 1][3];
            partials[((size_t)(s - 1) * BS + b) * NSLAB + sl] = dtot;
        }
    }

    // chunk-end snapshot: own rows from fin LDS buffer (self-written; no
    // extra regs held across the loop -> no spill). Coalesced 512 B/wave.
    const int finB = (W & 1) ? BUFB : 0;
    char* slotC = reinterpret_cast<char*>(slots) + (size_t)(q & 1) * SLOTB;
    #pragma unroll
    for (int k = 0; k < 4; ++k) if (k < nr)
        *reinterpret_cast<uint2*>(slotC + rowByte[k]) =
            *reinterpret_cast<const uint2*>(Xc + r0b + ((k << 11) + finB));
}

// ---------------------------------------------------------------------------
// findS: separate dispatch (kernel boundary = visibility). R4-verbatim.
// ---------------------------------------------------------------------------
__global__ void findS_kernel(const float* __restrict__ partials,
                             int* __restrict__ ctrl, int smax) {
    if (ctrl[2] != 0) return;
    const int lane = threadIdx.x;
    const float tol_bf = bf2f(f2bf(1e-5f));
    int S = -1;
    for (int s = 1; s <= smax; ++s) {
        const float* p = partials + ((size_t)(s - 1) * BS + lane) * NSLAB;
        float t = 0.f;
        #pragma unroll
        for (int k = 0; k < NSLAB; ++k) t += p[k];
        const float lnorm = bf2f(f2bf(t / 261120.0f));
        if (__ballot(lnorm > tol_bf) == 0ULL) { S = s; break; }
    }
    if (S < 0 && smax == ITERS) S = ITERS;
    if (lane == 0 && S > 0) { ctrl[0] = S; ctrl[2] = 1; }
}

// ---------------------------------------------------------------------------
// copyfinal (fallback only, slots in d_out): resolved slot -> ws verbatim.
// ---------------------------------------------------------------------------
__global__ __launch_bounds__(256) void copyfinal_kernel(
        const int* __restrict__ ctrl, const u16* __restrict__ slots,
        u16* __restrict__ dst) {
    int T, slot, fromX0;
    resolveS(ctrl[0], T, slot, fromX0);
    if (fromX0) return;
    const uint4* src = reinterpret_cast<const uint4*>(slots + (size_t)slot * XB);
    uint4* d = reinterpret_cast<uint4*>(dst);
    const size_t n = XB / 8;
    for (size_t i = (size_t)blockIdx.x * 256 + threadIdx.x; i < n;
         i += (size_t)gridDim.x * 256)
        d[i] = src[i];
}

// ---------------------------------------------------------------------------
// phaseC: 16-feat geometry (64-B output rows), single-buffer phase-split,
// uint2 granularity, bounds(256,4) => 128-VGPR cap (no spill; runs once).
// Reads the 8-feat slab-major snapshot via layout translation; runs T<=7
// steps; writes fp32 output directly (fused convert).
// ring!=0: s0 = 2-slot ring base (use resolved slot); else single state.
// ---------------------------------------------------------------------------
__global__ __launch_bounds__(256, 4) void phaseC_kernel(
        const int* __restrict__ edge, const int* __restrict__ ctrl,
        const u16* __restrict__ s0, int ring, float* __restrict__ out) {
    __shared__ u16 X[BSTR2];

    int T, slot, fromX0;
    resolveS(ctrl[0], T, slot, fromX0);

    const int wg = blockIdx.x, b = wg >> 5, sl = wg & 31;   // sl = 16-feat slab
    const int tid = threadIdx.x;
    const int rg = tid >> 2;                 // row group 0..63
    const int l  = tid & 3;                  // quarter-row lane
    const int lbyte = l << 3;                // byte offset in 32-B row
    const int nr = (rg < 62) ? 8 : 7;        // rows rg+64k < 510
    char* Xc = reinterpret_cast<char*>(X);
    const u32 r0b = (u32)(rg * 32 + lbyte);  // own-row LDS byte base (+k<<11)

    // gather offsets, 16-feat mapping
    u32 offB[8][3];
    #pragma unroll
    for (int k = 0; k < 8; ++k) if (k < nr) {
        const int i = rg + (k << 6);
        const int* ep = edge + ((size_t)b * TOTAL + NTIPS + i) * 3;
        #pragma unroll
        for (int t = 0; t < 3; ++t) {
            const int e = ep[t];
            u32 off;
            if (e >= NTIPS)          off = (u32)((e - NTIPS) * ROWEL2);
            else if ((e >> 4) == sl) off = (u32)(ONE2 + (e & 15) * ROWEL2);
            else                     off = (u32)ZROW2;
            offB[k][t] = off * 2u + (u32)lbyte;
        }
    }

    if (fromX0) {
        for (int j = tid; j < XSEC2 / 2; j += 256)
            reinterpret_cast<u32*>(X)[j] = 0x3B003B00u;
    } else {
        // translate from 8-feat slab-major snapshot:
        // feats sl*16 + l*4 .. +4 live in slab sl8 = sl*2 + (l>>1),
        // row bytes (l&1)*8 .. +8
        const char* src = reinterpret_cast<const char*>(s0)
                        + (ring ? (size_t)slot * SLOTB : (size_t)0);
        const u32 sb = (u32)(b * NSLAB + sl * 2 + (l >> 1)) * (u32)WGB
                     + (u32)((l & 1) << 3);
        #pragma unroll
        for (int k = 0; k < 8; ++k) if (k < nr) {
            const int r = rg + (k << 6);
            *reinterpret_cast<uint2*>(Xc + r0b + (k << 11)) =
                *reinterpret_cast<const uint2*>(src + sb + (u32)(r * 16));
        }
    }
    for (int j = tid; j < 17 * ROWEL2; j += 256) {
        const int row = j >> 4, col = j & 15;
        X[ONE2 + j] = (row == col) ? (u16)0x3F80 : (u16)0;
    }
    __syncthreads();

    for (int t = 1; t <= T; ++t) {
        uint2 nv[8];
        #pragma unroll
        for (int k = 0; k < 8; ++k) if (k < nr) {
            const uint2 g0 = *reinterpret_cast<const uint2*>(Xc + offB[k][0]);
            const uint2 g1 = *reinterpret_cast<const uint2*>(Xc + offB[k][1]);
            const uint2 g2 = *reinterpret_cast<const uint2*>(Xc + offB[k][2]);
            nv[k].x = stepND(g0.x, g1.x, g2.x);
            nv[k].y = stepND(g0.y, g1.y, g2.y);
        }
        __syncthreads();                      // all reads done
        #pragma unroll
        for (int k = 0; k < 8; ++k) if (k < nr)
            *reinterpret_cast<uint2*>(Xc + r0b + (k << 11)) = nv[k];
        __syncthreads();                      // state published
    }

    // fused output: WG owns feature cols [sl*16, sl*16+16) of tree b.
    float* obase = out + (size_t)b * TOTAL * NTIPS + sl * 16;
    for (int j = tid; j < NTIPS * 4; j += 256) {     // identity rows
        const int r = j >> 2, c4 = (j & 3) << 2;
        const int fc = sl * 16 + c4;
        float4 v;
        v.x = (r == fc + 0) ? 1.f : 0.f;
        v.y = (r == fc + 1) ? 1.f : 0.f;
        v.z = (r == fc + 2) ? 1.f : 0.f;
        v.w = (r == fc + 3) ? 1.f : 0.f;
        *reinterpret_cast<float4*>(obase + (size_t)r * NTIPS + c4) = v;
    }
    float* xbase = obase + (size_t)NTIPS * NTIPS;    // X rows from LDS
    for (int j = tid; j < DIM * 4; j += 256) {
        const int r = j >> 2, c4 = (j & 3) << 2;
        const ushort4 a = *reinterpret_cast<const ushort4*>(&X[r * ROWEL2 + c4]);
        float4 v;
        v.x = bf2f(a.x); v.y = bf2f(a.y); v.z = bf2f(a.z); v.w = bf2f(a.w);
        *reinterpret_cast<float4*>(xbase + (size_t)r * NTIPS + c4) = v;
    }
}

extern "C" void kernel_launch(void* const* d_in, const int* in_sizes, int n_in,
                              void* d_out, int out_size, void* d_ws, size_t ws_size,
                              hipStream_t stream) {
    const int* edge = (const int*)d_in[1];       // (BS, TOTAL, 3) int32
    float* out = (float*)d_out;
    const size_t partB = NPART * sizeof(float);

    static const int sBegs[8] = {1, 5, 9, 13, 21, 29, 37, 45};
    static const int Ws[8]    = {4, 4, 4, 8, 8, 8, 8, 6};

    if (ws_size >= 2 * SLOTB + partB + 256) {
        // ---- primary: 2-slot ring in ws ----
        u16*   slots    = (u16*)d_ws;
        float* partials = (float*)((char*)d_ws + 2 * SLOTB);
        int*   ctrl     = (int*)((char*)partials + partB);
        hipMemsetAsync(ctrl, 0, 4 * sizeof(int), stream);
        for (int i = 0; i < 8; ++i) {
            const int q = i + 1, sb = sBegs[i];
            if (Ws[i] == 4)
                chunk3_kernel<4><<<NWG, 256, 0, stream>>>(edge, partials, ctrl,
                                                          slots, q, sb);
            else if (Ws[i] == 8)
                chunk3_kernel<8><<<NWG, 256, 0, stream>>>(edge, partials, ctrl,
                                                          slots, q, sb);
            else
                chunk3_kernel<6><<<NWG, 256, 0, stream>>>(edge, partials, ctrl,
                                                          slots, q, sb);
            findS_kernel<<<1, 64, 0, stream>>>(partials, ctrl, sb + Ws[i] - 1);
        }
        phaseC_kernel<<<NWG2, 256, 0, stream>>>(edge, ctrl, slots, 1, out);
    } else {
        // ---- fallback: 2-slot ring in d_out, resolved slot copied to ws ----
        u16*   slots    = (u16*)d_out;
        u16*   finalX   = (u16*)d_ws;
        float* partials = (float*)((char*)d_ws + SLOTB);
        int*   ctrl     = (int*)((char*)partials + partB);
        hipMemsetAsync(ctrl, 0, 4 * sizeof(int), stream);
        for (int i = 0; i < 8; ++i) {
            const int q = i + 1, sb = sBegs[i];
            if (Ws[i] == 4)
                chunk3_kernel<4><<<NWG, 256, 0, stream>>>(edge, partials, ctrl,
                                                          slots, q, sb);
            else if (Ws[i] == 8)
                chunk3_kernel<8><<<NWG, 256, 0, stream>>>(edge, partials, ctrl,
                                                          slots, q, sb);
            else
                chunk3_kernel<6><<<NWG, 256, 0, stream>>>(edge, partials, ctrl,
                                                          slots, q, sb);
            findS_kernel<<<1, 64, 0, stream>>>(partials, ctrl, sb + Ws[i] - 1);
        }
        copyfinal_kernel<<<2048, 256, 0, stream>>>(ctrl, slots, finalX);
        phaseC_kernel<<<NWG2, 256, 0, stream>>>(edge, ctrl, finalX, 0, out);
    }
}

// Round 9
// 268.400 us; speedup vs baseline: 3.5375x; 1.1407x over previous
//
#include <hip/hip_runtime.h>

// ---- problem geometry ----
#define NTIPS 512
#define DIM   510                     // internal nodes = ntips - 2
#define TOTAL 1022
#define BS    64
#define ITERS 50

// ---- chunk config: 8-feat slabs (R4/R7-proven uint2 body), double-buffer ----
#define NSLAB 64
#define NWG   (BS * NSLAB)            // 4096 workgroups
#define NPART ((size_t)ITERS * BS * NSLAB)
#define ROWEL 8                       // u16 per row-slab (16 B)
#define XSEC   (DIM * ROWEL)          // 4080 u16
#define ONEOFF XSEC                   // 8 one-hot const rows
#define ZROW   (XSEC + 8 * ROWEL)     // all-zero const row
#define BSTRIDE (XSEC + 9 * ROWEL)    // 4152 u16 per LDS buffer
#define BUFB   (BSTRIDE * 2)          // 8304 B per buffer (2 buffers = 16.6KB)
#define WGB    (DIM * ROWEL * 2)      // 8160 B per WG region in a slot
#define XB     ((size_t)BS * DIM * NTIPS)  // u16 per snapshot slot
#define SLOTB  (XB * 2)               // 33.4 MB per slot

// ---- phaseC config: 16-feat slabs, single-buffer ----
#define NSLAB2 32
#define NWG2   (BS * NSLAB2)          // 2048 workgroups
#define ROWEL2 16
#define XSEC2  (DIM * ROWEL2)         // 8160 u16
#define ONE2   XSEC2
#define ZROW2  (XSEC2 + 16 * ROWEL2)
#define BSTR2  (XSEC2 + 17 * ROWEL2)  // 8432 u16 = 16864 B

typedef unsigned short u16;
typedef unsigned int   u32;
typedef float f32x2 __attribute__((ext_vector_type(2)));

// bf16 RNE helpers (validated chain)
__device__ __forceinline__ u16 f2bf(float x) {
    u32 u = __float_as_uint(x);
    return (u16)((u + 0x7FFFu + ((u >> 16) & 1u)) >> 16);
}
__device__ __forceinline__ float bf2f(u16 h) { return __uint_as_float(((u32)h) << 16); }
__device__ __forceinline__ float bflo(u32 p) { return __uint_as_float(p << 16); }
__device__ __forceinline__ float bfhi(u32 p) { return __uint_as_float(p & 0xFFFF0000u); }
__device__ __forceinline__ f32x2 unpk(u32 p) {
    f32x2 r; r.x = bflo(p); r.y = bfhi(p); return r;
}

#if defined(__has_builtin)
#  if __has_builtin(__builtin_amdgcn_cvt_pk_bf16_f32)
#    define HAVE_PKBF 1
#  endif
#endif
#ifdef HAVE_PKBF
typedef __bf16 bf16x2 __attribute__((ext_vector_type(2)));
__device__ __forceinline__ u32 pkbf(float a, float b) {   // lo=a, hi=b, RNE
    bf16x2 r = __builtin_amdgcn_cvt_pk_bf16_f32(a, b);
    return __builtin_bit_cast(u32, r);
}
#else
__device__ __forceinline__ u32 pkbf(float a, float b) {
    return (u32)f2bf(a) | ((u32)f2bf(b) << 16);
}
#endif

// correctly-rounded f32 /3 (Markstein mul+2fma) — R2..R7-validated
__device__ __forceinline__ f32x2 div3v(f32x2 x) {
    const float C = 0x1.555556p-2f;               // RN(1/3)
    f32x2 q0, r, q;
    q0.x = x.x * C;             q0.y = x.y * C;
    r.x = fmaf(-3.f, q0.x, x.x); r.y = fmaf(-3.f, q0.y, x.y);
    q.x = fmaf(r.x, C, q0.x);    q.y = fmaf(r.y, C, q0.y);
    return q;
}
// no-delta packed-pair step (phaseC)
__device__ __forceinline__ u32 stepND(u32 a0, u32 a1, u32 a2) {
    const f32x2 a = (unpk(a0) + unpk(a1)) + unpk(a2);
    const f32x2 q = div3v(a);
    return pkbf(q.x, q.y);
}

// LDS-only barrier (R3..R7-validated): no vmcnt drain
__device__ __forceinline__ void barrier_lds_only() {
    __builtin_amdgcn_sched_barrier(0);
    asm volatile("s_waitcnt lgkmcnt(0)" ::: "memory");
    __builtin_amdgcn_s_barrier();
    __builtin_amdgcn_sched_barrier(0);
}

// checkpoints: step {6,12,20,28,36,44,50} -> slot {1,0,1,0,1,0,1}
__device__ __forceinline__ void resolveS(int S, int& T, int& slot, int& fromX0) {
    const int cps[7] = {6, 12, 20, 28, 36, 44, 50};
    fromX0 = 0; T = S; slot = 0;
    int cp = 0;
    #pragma unroll
    for (int i = 0; i < 7; ++i)
        if (cps[i] <= S) { cp = cps[i]; slot = (i + 1) & 1; }
    if (cp == 0) fromX0 = 1;
    else         T = S - cp;
}

// gather offsets for 8-feat slabs (BYTE units, buffer-relative) — R4-proven
__device__ __forceinline__ void make_offsets8(const int* __restrict__ edge,
        int b, int sl, int rg, int lbyte, int nr, u32 offB[4][3]) {
    #pragma unroll
    for (int k = 0; k < 4; ++k) if (k < nr) {
        const int i = rg + 128 * k;
        const int* ep = edge + ((size_t)b * TOTAL + NTIPS + i) * 3;
        #pragma unroll
        for (int t = 0; t < 3; ++t) {
            const int e = ep[t];
            u32 off;
            if (e >= NTIPS)          off = (u32)((e - NTIPS) * ROWEL);
            else if ((e >> 3) == sl) off = (u32)(ONEOFF + (e & 7) * ROWEL);
            else                     off = (u32)ZROW;
            offB[k][t] = off * 2u + (u32)lbyte;
        }
    }
}

__device__ __forceinline__ void init_const_rows8(u16* X, int tid) {
    for (int j = tid; j < 9 * ROWEL; j += 256) {
        const int row = j >> 3, col = j & 7;
        const u16 v = (row == col) ? (u16)0x3F80 : (u16)0;  // row 8 = zeros
        X[ONEOFF + j] = v;
        X[BSTRIDE + ONEOFF + j] = v;
    }
}

// ---------------------------------------------------------------------------
// chunk3: R7-verbatim proven body. W steps, chunk-end snapshot -> slot q&1.
// ---------------------------------------------------------------------------
template<int W>
__global__ __launch_bounds__(256, 8) void chunk3_kernel(
        const int* __restrict__ edge, float* __restrict__ partials,
        const int* __restrict__ ctrl, u16* __restrict__ slots, int q, int sBeg) {
    if (q >= 2 && ctrl[2] != 0) return;          // converged: skip

    __shared__ u16 X[2 * BSTRIDE];
    __shared__ float redL[2][4];

    const int wg = blockIdx.x, b = wg >> 6, sl = wg & 63;
    const int tid = threadIdx.x, rg = tid >> 1;
    const int lbyte = (tid & 1) << 3;
    const int nr = (rg < 126) ? 4 : 3;
    char* Xc = reinterpret_cast<char*>(X);
    const u32 r0b = (u32)(rg * 16 + lbyte);

    u32 offB[4][3];
    make_offsets8(edge, b, sl, rg, lbyte, nr, offB);

    u32 rowByte[4];
    #pragma unroll
    for (int k = 0; k < 4; ++k)
        rowByte[k] = (u32)wg * (u32)WGB + (u32)((rg + 128 * k) * 16) + (u32)lbyte;

    if (q == 1) {
        for (int j = tid; j < XSEC / 2; j += 256)
            reinterpret_cast<u32*>(X)[j] = 0x3B003B00u;   // X0 = bf16(1/512)
    } else {
        const char* src0 = reinterpret_cast<const char*>(slots)
                         + (size_t)((q - 1) & 1) * SLOTB;
        #pragma unroll
        for (int k = 0; k < 4; ++k) if (k < nr)
            *reinterpret_cast<uint2*>(Xc + r0b + (k << 11)) =
                *reinterpret_cast<const uint2*>(src0 + rowByte[k]);
    }
    init_const_rows8(X, tid);

    f32x2 old01[4], old23[4];
    #pragma unroll
    for (int k = 0; k < 4; ++k) if (k < nr) {
        const uint2 ov = *reinterpret_cast<const uint2*>(Xc + r0b + (k << 11));
        old01[k] = unpk(ov.x); old23[k] = unpk(ov.y);
    }
    __syncthreads();

    #pragma unroll
    for (int u = 0; u < W; ++u) {
        const int s = sBeg + u;
        const int srcB = (u & 1) ? BUFB : 0;
        const int dstB = ((u + 1) & 1) ? BUFB : 0;
        float dacc = 0.f;
        #pragma unroll
        for (int k = 0; k < 4; ++k) if (k < nr) {
            const uint2 g0 = *reinterpret_cast<const uint2*>(Xc + offB[k][0] + srcB);
            const uint2 g1 = *reinterpret_cast<const uint2*>(Xc + offB[k][1] + srcB);
            const uint2 g2 = *reinterpret_cast<const uint2*>(Xc + offB[k][2] + srcB);
            const f32x2 a01 = (unpk(g0.x) + unpk(g1.x)) + unpk(g2.x);
            const f32x2 a23 = (unpk(g0.y) + unpk(g1.y)) + unpk(g2.y);
            const f32x2 q01 = div3v(a01), q23 = div3v(a23);
            uint2 nv;
            nv.x = pkbf(q01.x, q01.y);
            nv.y = pkbf(q23.x, q23.y);
            *reinterpret_cast<uint2*>(Xc + r0b + ((k << 11) + dstB)) = nv;
            const f32x2 n01 = unpk(nv.x), n23 = unpk(nv.y);
            const f32x2 d01v = n01 - old01[k];
            const f32x2 d23v = n23 - old23[k];
            const u32 d01 = pkbf(d01v.x, d01v.y);
            const u32 d23 = pkbf(d23v.x, d23v.y);
            dacc += fabsf(bflo(d01));
            dacc += fabsf(bfhi(d01));
            dacc += fabsf(bflo(d23));
            dacc += fabsf(bfhi(d23));
            old01[k] = n01; old23[k] = n23;
        }
        #pragma unroll
        for (int off = 32; off > 0; off >>= 1) dacc += __shfl_down(dacc, off);
        if ((tid & 63) == 0) redL[u & 1][tid >> 6] = dacc;
        barrier_lds_only();
        if (tid == 0) {
            const float dtot = ((redL[u & 1][0] + redL[u & 1][1])
                                + redL[u & 1][2]) + redL[u & 1][3];
            partials[((size_t)(s - 1) * BS + b) * NSLAB + sl] = dtot;
        }
    }

    const int finB = (W & 1) ? BUFB : 0;
    char* slotC = reinterpret_cast<char*>(slots) + (size_t)(q & 1) * SLOTB;
    #pragma unroll
    for (int k = 0; k < 4; ++k) if (k < nr)
        *reinterpret_cast<uint2*>(slotC + rowByte[k]) =
            *reinterpret_cast<const uint2*>(Xc + r0b + ((k << 11) + finB));
}

// ---------------------------------------------------------------------------
// tail: steps 13..50 in ONE gated launch (runtime loop). Snapshots at
// checkpoints 20/28/36/44/50 (alternating slots) keep phaseC's T <= 7.
// Same step body as chunk3; reloads checkpoint-12 (slot 0).
// ---------------------------------------------------------------------------
__global__ __launch_bounds__(256, 8) void tail_kernel(
        const int* __restrict__ edge, float* __restrict__ partials,
        const int* __restrict__ ctrl, u16* __restrict__ slots) {
    if (ctrl[2] != 0) return;                    // common case: skip

    __shared__ u16 X[2 * BSTRIDE];
    __shared__ float redL[2][4];

    const int wg = blockIdx.x, b = wg >> 6, sl = wg & 63;
    const int tid = threadIdx.x, rg = tid >> 1;
    const int lbyte = (tid & 1) << 3;
    const int nr = (rg < 126) ? 4 : 3;
    char* Xc = reinterpret_cast<char*>(X);
    const u32 r0b = (u32)(rg * 16 + lbyte);

    u32 offB[4][3];
    make_offsets8(edge, b, sl, rg, lbyte, nr, offB);

    u32 rowByte[4];
    #pragma unroll
    for (int k = 0; k < 4; ++k)
        rowByte[k] = (u32)wg * (u32)WGB + (u32)((rg + 128 * k) * 16) + (u32)lbyte;

    {   // reload checkpoint step 12 (slot 0)
        const char* src0 = reinterpret_cast<const char*>(slots);
        #pragma unroll
        for (int k = 0; k < 4; ++k) if (k < nr)
            *reinterpret_cast<uint2*>(Xc + r0b + (k << 11)) =
                *reinterpret_cast<const uint2*>(src0 + rowByte[k]);
    }
    init_const_rows8(X, tid);

    f32x2 old01[4], old23[4];
    #pragma unroll
    for (int k = 0; k < 4; ++k) if (k < nr) {
        const uint2 ov = *reinterpret_cast<const uint2*>(Xc + r0b + (k << 11));
        old01[k] = unpk(ov.x); old23[k] = unpk(ov.y);
    }
    __syncthreads();

    u32 srcB = 0;
    int cpSlot = 1;
    for (int s = 13; s <= 50; ++s) {
        const u32 dstB = srcB ^ (u32)BUFB;
        float dacc = 0.f;
        #pragma unroll
        for (int k = 0; k < 4; ++k) if (k < nr) {
            const uint2 g0 = *reinterpret_cast<const uint2*>(Xc + offB[k][0] + srcB);
            const uint2 g1 = *reinterpret_cast<const uint2*>(Xc + offB[k][1] + srcB);
            const uint2 g2 = *reinterpret_cast<const uint2*>(Xc + offB[k][2] + srcB);
            const f32x2 a01 = (unpk(g0.x) + unpk(g1.x)) + unpk(g2.x);
            const f32x2 a23 = (unpk(g0.y) + unpk(g1.y)) + unpk(g2.y);
            const f32x2 q01 = div3v(a01), q23 = div3v(a23);
            uint2 nv;
            nv.x = pkbf(q01.x, q01.y);
            nv.y = pkbf(q23.x, q23.y);
            *reinterpret_cast<uint2*>(Xc + r0b + ((k << 11) + dstB)) = nv;
            const f32x2 n01 = unpk(nv.x), n23 = unpk(nv.y);
            const f32x2 d01v = n01 - old01[k];
            const f32x2 d23v = n23 - old23[k];
            const u32 d01 = pkbf(d01v.x, d01v.y);
            const u32 d23 = pkbf(d23v.x, d23v.y);
            dacc += fabsf(bflo(d01));
            dacc += fabsf(bfhi(d01));
            dacc += fabsf(bflo(d23));
            dacc += fabsf(bfhi(d23));
            old01[k] = n01; old23[k] = n23;
        }
        #pragma unroll
        for (int off = 32; off > 0; off >>= 1) dacc += __shfl_down(dacc, off);
        if ((tid & 63) == 0) redL[s & 1][tid >> 6] = dacc;
        barrier_lds_only();
        if (tid == 0) {
            const float dtot = ((redL[s & 1][0] + redL[s & 1][1])
                                + redL[s & 1][2]) + redL[s & 1][3];
            partials[((size_t)(s - 1) * BS + b) * NSLAB + sl] = dtot;
        }
        if (s == 20 || s == 28 || s == 36 || s == 44 || s == 50) {
            char* slotC = reinterpret_cast<char*>(slots)
                        + (size_t)cpSlot * SLOTB;
            #pragma unroll
            for (int k = 0; k < 4; ++k) if (k < nr)
                *reinterpret_cast<uint2*>(slotC + rowByte[k]) =
                    *reinterpret_cast<const uint2*>(Xc + r0b + ((k << 11) + dstB));
            cpSlot ^= 1;
        }
        srcB = dstB;
    }
}

// ---------------------------------------------------------------------------
// findS: incremental (ctrl[3] = next unscanned s). EXACT decision math.
// ---------------------------------------------------------------------------
__global__ void findS_kernel(const float* __restrict__ partials,
                             int* __restrict__ ctrl, int smax) {
    if (ctrl[2] != 0) return;
    const int lane = threadIdx.x;
    const int sStart = (ctrl[3] > 1) ? ctrl[3] : 1;
    const float tol_bf = bf2f(f2bf(1e-5f));
    int S = -1;
    for (int s = sStart; s <= smax; ++s) {
        const float* p = partials + ((size_t)(s - 1) * BS + lane) * NSLAB;
        float t = 0.f;
        #pragma unroll
        for (int k = 0; k < NSLAB; ++k) t += p[k];
        const float lnorm = bf2f(f2bf(t / 261120.0f));
        if (__ballot(lnorm > tol_bf) == 0ULL) { S = s; break; }
    }
    if (S < 0 && smax == ITERS) S = ITERS;
    if (lane == 0) {
        if (S > 0) { ctrl[0] = S; ctrl[2] = 1; }
        else         ctrl[3] = smax + 1;
    }
}

// ---------------------------------------------------------------------------
// ident: identity block (rows 0..511, all trees) — row-contiguous, full BW.
// Runs first; independent of S.
// ---------------------------------------------------------------------------
__global__ __launch_bounds__(256) void ident_kernel(float* __restrict__ out) {
    const size_t nf4 = (size_t)BS * NTIPS * NTIPS / 4;   // 4,194,304 float4
    for (size_t i = (size_t)blockIdx.x * 256 + threadIdx.x; i < nf4;
         i += (size_t)gridDim.x * 256) {
        const u32 b   = (u32)(i >> 16);          // 65536 float4 per tree
        const u32 rem = (u32)(i & 65535u);
        const u32 r   = rem >> 7;                // 128 float4 per row
        const u32 c0  = (rem & 127u) << 2;
        float4 v;
        v.x = (r == c0 + 0) ? 1.f : 0.f;
        v.y = (r == c0 + 1) ? 1.f : 0.f;
        v.z = (r == c0 + 2) ? 1.f : 0.f;
        v.w = (r == c0 + 3) ? 1.f : 0.f;
        *reinterpret_cast<float4*>(out + (size_t)b * TOTAL * NTIPS
                                   + (size_t)r * NTIPS + c0) = v;
    }
}

// ---------------------------------------------------------------------------
// copyfinal (fallback only, slots in d_out): resolved slot -> ws verbatim.
// ---------------------------------------------------------------------------
__global__ __launch_bounds__(256) void copyfinal_kernel(
        const int* __restrict__ ctrl, const u16* __restrict__ slots,
        u16* __restrict__ dst) {
    int T, slot, fromX0;
    resolveS(ctrl[0], T, slot, fromX0);
    if (fromX0) return;
    const uint4* src = reinterpret_cast<const uint4*>(slots + (size_t)slot * XB);
    uint4* d = reinterpret_cast<uint4*>(dst);
    const size_t n = XB / 8;
    for (size_t i = (size_t)blockIdx.x * 256 + threadIdx.x; i < n;
         i += (size_t)gridDim.x * 256)
        d[i] = src[i];
}

// ---------------------------------------------------------------------------
// phaseCX: resume from resolved checkpoint, run T (<=7) steps, write ONLY
// the X block (rows 512..1021) as fp32. R7-proven translation + step body.
// ---------------------------------------------------------------------------
__global__ __launch_bounds__(256, 4) void phaseCX_kernel(
        const int* __restrict__ edge, const int* __restrict__ ctrl,
        const u16* __restrict__ s0, int ring, float* __restrict__ out) {
    __shared__ u16 X[BSTR2];

    int T, slot, fromX0;
    resolveS(ctrl[0], T, slot, fromX0);

    const int wg = blockIdx.x, b = wg >> 5, sl = wg & 31;   // 16-feat slab
    const int tid = threadIdx.x;
    const int rg = tid >> 2;                 // row group 0..63
    const int l  = tid & 3;
    const int lbyte = l << 3;
    const int nr = (rg < 62) ? 8 : 7;
    char* Xc = reinterpret_cast<char*>(X);
    const u32 r0b = (u32)(rg * 32 + lbyte);

    u32 offB[8][3];
    #pragma unroll
    for (int k = 0; k < 8; ++k) if (k < nr) {
        const int i = rg + (k << 6);
        const int* ep = edge + ((size_t)b * TOTAL + NTIPS + i) * 3;
        #pragma unroll
        for (int t = 0; t < 3; ++t) {
            const int e = ep[t];
            u32 off;
            if (e >= NTIPS)          off = (u32)((e - NTIPS) * ROWEL2);
            else if ((e >> 4) == sl) off = (u32)(ONE2 + (e & 15) * ROWEL2);
            else                     off = (u32)ZROW2;
            offB[k][t] = off * 2u + (u32)lbyte;
        }
    }

    if (fromX0) {
        for (int j = tid; j < XSEC2 / 2; j += 256)
            reinterpret_cast<u32*>(X)[j] = 0x3B003B00u;
    } else {
        // translate from 8-feat slab-major snapshot (R7-proven)
        const char* src = reinterpret_cast<const char*>(s0)
                        + (ring ? (size_t)slot * SLOTB : (size_t)0);
        const u32 sb = (u32)(b * NSLAB + sl * 2 + (l >> 1)) * (u32)WGB
                     + (u32)((l & 1) << 3);
        #pragma unroll
        for (int k = 0; k < 8; ++k) if (k < nr) {
            const int r = rg + (k << 6);
            *reinterpret_cast<uint2*>(Xc + r0b + (k << 11)) =
                *reinterpret_cast<const uint2*>(src + sb + (u32)(r * 16));
        }
    }
    for (int j = tid; j < 17 * ROWEL2; j += 256) {
        const int row = j >> 4, col = j & 15;
        X[ONE2 + j] = (row == col) ? (u16)0x3F80 : (u16)0;
    }
    __syncthreads();

    for (int t = 1; t <= T; ++t) {
        uint2 nv[8];
        #pragma unroll
        for (int k = 0; k < 8; ++k) if (k < nr) {
            const uint2 g0 = *reinterpret_cast<const uint2*>(Xc + offB[k][0]);
            const uint2 g1 = *reinterpret_cast<const uint2*>(Xc + offB[k][1]);
            const uint2 g2 = *reinterpret_cast<const uint2*>(Xc + offB[k][2]);
            nv[k].x = stepND(g0.x, g1.x, g2.x);
            nv[k].y = stepND(g0.y, g1.y, g2.y);
        }
        __syncthreads();
        #pragma unroll
        for (int k = 0; k < 8; ++k) if (k < nr)
            *reinterpret_cast<uint2*>(Xc + r0b + (k << 11)) = nv[k];
        __syncthreads();
    }

    // X block only: WG owns feature cols [sl*16, sl*16+16) of tree b.
    float* xbase = out + (size_t)b * TOTAL * NTIPS
                 + (size_t)NTIPS * NTIPS + sl * 16;
    for (int j = tid; j < DIM * 4; j += 256) {
        const int r = j >> 2, c4 = (j & 3) << 2;
        const ushort4 a = *reinterpret_cast<const ushort4*>(&X[r * ROWEL2 + c4]);
        float4 v;
        v.x = bf2f(a.x); v.y = bf2f(a.y); v.z = bf2f(a.z); v.w = bf2f(a.w);
        *reinterpret_cast<float4*>(xbase + (size_t)r * NTIPS + c4) = v;
    }
}

extern "C" void kernel_launch(void* const* d_in, const int* in_sizes, int n_in,
                              void* d_out, int out_size, void* d_ws, size_t ws_size,
                              hipStream_t stream) {
    const int* edge = (const int*)d_in[1];       // (BS, TOTAL, 3) int32
    float* out = (float*)d_out;
    const size_t partB = NPART * sizeof(float);

    if (ws_size >= 2 * SLOTB + partB + 256) {
        // ---- primary: 2-slot ring in ws ----
        u16*   slots    = (u16*)d_ws;
        float* partials = (float*)((char*)d_ws + 2 * SLOTB);
        int*   ctrl     = (int*)((char*)partials + partB);
        hipMemsetAsync(ctrl, 0, 4 * sizeof(int), stream);
        ident_kernel<<<2048, 256, 0, stream>>>(out);
        chunk3_kernel<6><<<NWG, 256, 0, stream>>>(edge, partials, ctrl,
                                                  slots, 1, 1);
        findS_kernel<<<1, 64, 0, stream>>>(partials, ctrl, 6);
        chunk3_kernel<6><<<NWG, 256, 0, stream>>>(edge, partials, ctrl,
                                                  slots, 2, 7);
        findS_kernel<<<1, 64, 0, stream>>>(partials, ctrl, 12);
        tail_kernel<<<NWG, 256, 0, stream>>>(edge, partials, ctrl, slots);
        findS_kernel<<<1, 64, 0, stream>>>(partials, ctrl, 50);
        phaseCX_kernel<<<NWG2, 256, 0, stream>>>(edge, ctrl, slots, 1, out);
    } else {
        // ---- fallback: 2-slot ring in d_out; extract, then ident, then X ----
        u16*   slots    = (u16*)d_out;
        u16*   finalX   = (u16*)d_ws;
        float* partials = (float*)((char*)d_ws + SLOTB);
        int*   ctrl     = (int*)((char*)partials + partB);
        hipMemsetAsync(ctrl, 0, 4 * sizeof(int), stream);
        chunk3_kernel<6><<<NWG, 256, 0, stream>>>(edge, partials, ctrl,
                                                  slots, 1, 1);
        findS_kernel<<<1, 64, 0, stream>>>(partials, ctrl, 6);
        chunk3_kernel<6><<<NWG, 256, 0, stream>>>(edge, partials, ctrl,
                                                  slots, 2, 7);
        findS_kernel<<<1, 64, 0, stream>>>(partials, ctrl, 12);
        tail_kernel<<<NWG, 256, 0, stream>>>(edge, partials, ctrl, slots);
        findS_kernel<<<1, 64, 0, stream>>>(partials, ctrl, 50);
        copyfinal_kernel<<<2048, 256, 0, stream>>>(ctrl, slots, finalX);
        ident_kernel<<<2048, 256, 0, stream>>>(out);
        phaseCX_kernel<<<NWG2, 256, 0, stream>>>(edge, ctrl, finalX, 0, out);
    }
}

// Round 10
// 247.143 us; speedup vs baseline: 3.8418x; 1.0860x over previous
//
#include <hip/hip_runtime.h>

// ---- problem geometry ----
#define NTIPS 512
#define DIM   510                     // internal nodes = ntips - 2
#define TOTAL 1022
#define BS    64
#define ITERS 50

// ---- chunk config: 8-feat slabs (R4/R7/R9-proven uint2 body), dbuf ----
#define NSLAB 64
#define NWG   (BS * NSLAB)            // 4096 workgroups
#define NPART ((size_t)ITERS * BS * NSLAB)
#define ROWEL 8                       // u16 per row-slab (16 B)
#define XSEC   (DIM * ROWEL)          // 4080 u16
#define ONEOFF XSEC                   // 8 one-hot const rows
#define ZROW   (XSEC + 8 * ROWEL)     // all-zero const row
#define BSTRIDE (XSEC + 9 * ROWEL)    // 4152 u16 per LDS buffer
#define BUFB   (BSTRIDE * 2)          // 8304 B per buffer (2 buffers = 16.6KB)
#define WGB    (DIM * ROWEL * 2)      // 8160 B per WG region in a slot
#define XB     ((size_t)BS * DIM * NTIPS)  // u16 per snapshot slot
#define SLOTB  (XB * 2)               // 33.4 MB per slot

// ---- phaseC config: 16-feat slabs, single-buffer ----
#define NSLAB2 32
#define NWG2   (BS * NSLAB2)          // 2048 workgroups
#define ROWEL2 16
#define XSEC2  (DIM * ROWEL2)         // 8160 u16
#define ONE2   XSEC2
#define ZROW2  (XSEC2 + 16 * ROWEL2)
#define BSTR2  (XSEC2 + 17 * ROWEL2)  // 8432 u16 = 16864 B

typedef unsigned short u16;
typedef unsigned int   u32;
typedef float f32x2 __attribute__((ext_vector_type(2)));

// bf16 RNE helpers (validated chain)
__device__ __forceinline__ u16 f2bf(float x) {
    u32 u = __float_as_uint(x);
    return (u16)((u + 0x7FFFu + ((u >> 16) & 1u)) >> 16);
}
__device__ __forceinline__ float bf2f(u16 h) { return __uint_as_float(((u32)h) << 16); }
__device__ __forceinline__ float bflo(u32 p) { return __uint_as_float(p << 16); }
__device__ __forceinline__ float bfhi(u32 p) { return __uint_as_float(p & 0xFFFF0000u); }
__device__ __forceinline__ f32x2 unpk(u32 p) {
    f32x2 r; r.x = bflo(p); r.y = bfhi(p); return r;
}

#if defined(__has_builtin)
#  if __has_builtin(__builtin_amdgcn_cvt_pk_bf16_f32)
#    define HAVE_PKBF 1
#  endif
#endif
#ifdef HAVE_PKBF
typedef __bf16 bf16x2 __attribute__((ext_vector_type(2)));
__device__ __forceinline__ u32 pkbf(float a, float b) {   // lo=a, hi=b, RNE
    bf16x2 r = __builtin_amdgcn_cvt_pk_bf16_f32(a, b);
    return __builtin_bit_cast(u32, r);
}
#else
__device__ __forceinline__ u32 pkbf(float a, float b) {
    return (u32)f2bf(a) | ((u32)f2bf(b) << 16);
}
#endif

// correctly-rounded f32 /3 (Markstein mul+2fma) — R2..R9-validated
__device__ __forceinline__ f32x2 div3v(f32x2 x) {
    const float C = 0x1.555556p-2f;               // RN(1/3)
    f32x2 q0, r, q;
    q0.x = x.x * C;             q0.y = x.y * C;
    r.x = fmaf(-3.f, q0.x, x.x); r.y = fmaf(-3.f, q0.y, x.y);
    q.x = fmaf(r.x, C, q0.x);    q.y = fmaf(r.y, C, q0.y);
    return q;
}
// no-delta packed-pair step (phaseC)
__device__ __forceinline__ u32 stepND(u32 a0, u32 a1, u32 a2) {
    const f32x2 a = (unpk(a0) + unpk(a1)) + unpk(a2);
    const f32x2 q = div3v(a);
    return pkbf(q.x, q.y);
}

// LDS-only barrier (R3..R9-validated): no vmcnt drain
__device__ __forceinline__ void barrier_lds_only() {
    __builtin_amdgcn_sched_barrier(0);
    asm volatile("s_waitcnt lgkmcnt(0)" ::: "memory");
    __builtin_amdgcn_s_barrier();
    __builtin_amdgcn_sched_barrier(0);
}

// checkpoints: step {9,12,20,28,36,44,50} -> slot {1,0,1,0,1,0,1}
__device__ __forceinline__ void resolveS(int S, int& T, int& slot, int& fromX0) {
    const int cps[7] = {9, 12, 20, 28, 36, 44, 50};
    fromX0 = 0; T = S; slot = 0;
    int cp = 0;
    #pragma unroll
    for (int i = 0; i < 7; ++i)
        if (cps[i] <= S) { cp = cps[i]; slot = (i + 1) & 1; }
    if (cp == 0) fromX0 = 1;
    else         T = S - cp;
}

// gather offsets for 8-feat slabs (BYTE units, buffer-relative) — R4-proven
__device__ __forceinline__ void make_offsets8(const int* __restrict__ edge,
        int b, int sl, int rg, int lbyte, int nr, u32 offB[4][3]) {
    #pragma unroll
    for (int k = 0; k < 4; ++k) if (k < nr) {
        const int i = rg + 128 * k;
        const int* ep = edge + ((size_t)b * TOTAL + NTIPS + i) * 3;
        #pragma unroll
        for (int t = 0; t < 3; ++t) {
            const int e = ep[t];
            u32 off;
            if (e >= NTIPS)          off = (u32)((e - NTIPS) * ROWEL);
            else if ((e >> 3) == sl) off = (u32)(ONEOFF + (e & 7) * ROWEL);
            else                     off = (u32)ZROW;
            offB[k][t] = off * 2u + (u32)lbyte;
        }
    }
}

__device__ __forceinline__ void init_const_rows8(u16* X, int tid) {
    for (int j = tid; j < 9 * ROWEL; j += 256) {
        const int row = j >> 3, col = j & 7;
        const u16 v = (row == col) ? (u16)0x3F80 : (u16)0;  // row 8 = zeros
        X[ONEOFF + j] = v;
        X[BSTRIDE + ONEOFF + j] = v;
    }
}

// ---------------------------------------------------------------------------
// live12: steps 1..12 in ONE launch (merges R9's two W6 chunks — no
// inter-chunk 33MB snapshot->reload round-trip). Mid checkpoint at step 9
// (inline register store -> slot 1; its 33MB drains under steps 10-12's
// compute), end checkpoint at step 12 -> slot 0. R9-verbatim step body.
// ---------------------------------------------------------------------------
__global__ __launch_bounds__(256, 8) void live12_kernel(
        const int* __restrict__ edge, float* __restrict__ partials,
        u16* __restrict__ slots) {
    __shared__ u16 X[2 * BSTRIDE];
    __shared__ float redL[2][4];

    const int wg = blockIdx.x, b = wg >> 6, sl = wg & 63;
    const int tid = threadIdx.x, rg = tid >> 1;
    const int lbyte = (tid & 1) << 3;
    const int nr = (rg < 126) ? 4 : 3;
    char* Xc = reinterpret_cast<char*>(X);
    const u32 r0b = (u32)(rg * 16 + lbyte);

    u32 offB[4][3];
    make_offsets8(edge, b, sl, rg, lbyte, nr, offB);

    u32 rowByte[4];
    #pragma unroll
    for (int k = 0; k < 4; ++k)
        rowByte[k] = (u32)wg * (u32)WGB + (u32)((rg + 128 * k) * 16) + (u32)lbyte;

    for (int j = tid; j < XSEC / 2; j += 256)
        reinterpret_cast<u32*>(X)[j] = 0x3B003B00u;       // X0 = bf16(1/512)
    init_const_rows8(X, tid);

    f32x2 old01[4], old23[4];
    #pragma unroll
    for (int k = 0; k < 4; ++k) if (k < nr) {
        const uint2 ov = *reinterpret_cast<const uint2*>(Xc + r0b + (k << 11));
        old01[k] = unpk(ov.x); old23[k] = unpk(ov.y);
    }
    __syncthreads();

    char* slot1C = reinterpret_cast<char*>(slots) + SLOTB;   // step-9 cp
    #pragma unroll
    for (int u = 0; u < 12; ++u) {
        const int s = 1 + u;
        const int srcB = (u & 1) ? BUFB : 0;
        const int dstB = ((u + 1) & 1) ? BUFB : 0;
        float dacc = 0.f;
        #pragma unroll
        for (int k = 0; k < 4; ++k) if (k < nr) {
            const uint2 g0 = *reinterpret_cast<const uint2*>(Xc + offB[k][0] + srcB);
            const uint2 g1 = *reinterpret_cast<const uint2*>(Xc + offB[k][1] + srcB);
            const uint2 g2 = *reinterpret_cast<const uint2*>(Xc + offB[k][2] + srcB);
            const f32x2 a01 = (unpk(g0.x) + unpk(g1.x)) + unpk(g2.x);
            const f32x2 a23 = (unpk(g0.y) + unpk(g1.y)) + unpk(g2.y);
            const f32x2 q01 = div3v(a01), q23 = div3v(a23);
            uint2 nv;
            nv.x = pkbf(q01.x, q01.y);
            nv.y = pkbf(q23.x, q23.y);
            *reinterpret_cast<uint2*>(Xc + r0b + ((k << 11) + dstB)) = nv;
            if (u == 8)                              // step 9 checkpoint
                *reinterpret_cast<uint2*>(slot1C + rowByte[k]) = nv;
            const f32x2 n01 = unpk(nv.x), n23 = unpk(nv.y);
            const f32x2 d01v = n01 - old01[k];
            const f32x2 d23v = n23 - old23[k];
            const u32 d01 = pkbf(d01v.x, d01v.y);
            const u32 d23 = pkbf(d23v.x, d23v.y);
            dacc += fabsf(bflo(d01));
            dacc += fabsf(bfhi(d01));
            dacc += fabsf(bflo(d23));
            dacc += fabsf(bfhi(d23));
            old01[k] = n01; old23[k] = n23;
        }
        #pragma unroll
        for (int off = 32; off > 0; off >>= 1) dacc += __shfl_down(dacc, off);
        if ((tid & 63) == 0) redL[u & 1][tid >> 6] = dacc;
        barrier_lds_only();
        if (tid == 0) {
            const float dtot = ((redL[u & 1][0] + redL[u & 1][1])
                                + redL[u & 1][2]) + redL[u & 1][3];
            partials[((size_t)(s - 1) * BS + b) * NSLAB + sl] = dtot;
        }
    }

    // end checkpoint: step 12 (buffer 0) -> slot 0
    char* slot0C = reinterpret_cast<char*>(slots);
    #pragma unroll
    for (int k = 0; k < 4; ++k) if (k < nr)
        *reinterpret_cast<uint2*>(slot0C + rowByte[k]) =
            *reinterpret_cast<const uint2*>(Xc + r0b + (k << 11));
}

// ---------------------------------------------------------------------------
// tail: steps 13..50 in ONE gated launch. Checkpoints 20/28/36/44/50
// (alternating slots, start 1). Reloads checkpoint-12 (slot 0). R9-verbatim.
// ---------------------------------------------------------------------------
__global__ __launch_bounds__(256, 8) void tail_kernel(
        const int* __restrict__ edge, float* __restrict__ partials,
        const int* __restrict__ ctrl, u16* __restrict__ slots) {
    if (ctrl[2] != 0) return;                    // common case: skip

    __shared__ u16 X[2 * BSTRIDE];
    __shared__ float redL[2][4];

    const int wg = blockIdx.x, b = wg >> 6, sl = wg & 63;
    const int tid = threadIdx.x, rg = tid >> 1;
    const int lbyte = (tid & 1) << 3;
    const int nr = (rg < 126) ? 4 : 3;
    char* Xc = reinterpret_cast<char*>(X);
    const u32 r0b = (u32)(rg * 16 + lbyte);

    u32 offB[4][3];
    make_offsets8(edge, b, sl, rg, lbyte, nr, offB);

    u32 rowByte[4];
    #pragma unroll
    for (int k = 0; k < 4; ++k)
        rowByte[k] = (u32)wg * (u32)WGB + (u32)((rg + 128 * k) * 16) + (u32)lbyte;

    {   // reload checkpoint step 12 (slot 0)
        const char* src0 = reinterpret_cast<const char*>(slots);
        #pragma unroll
        for (int k = 0; k < 4; ++k) if (k < nr)
            *reinterpret_cast<uint2*>(Xc + r0b + (k << 11)) =
                *reinterpret_cast<const uint2*>(src0 + rowByte[k]);
    }
    init_const_rows8(X, tid);

    f32x2 old01[4], old23[4];
    #pragma unroll
    for (int k = 0; k < 4; ++k) if (k < nr) {
        const uint2 ov = *reinterpret_cast<const uint2*>(Xc + r0b + (k << 11));
        old01[k] = unpk(ov.x); old23[k] = unpk(ov.y);
    }
    __syncthreads();

    u32 srcB = 0;
    int cpSlot = 1;
    for (int s = 13; s <= 50; ++s) {
        const u32 dstB = srcB ^ (u32)BUFB;
        float dacc = 0.f;
        #pragma unroll
        for (int k = 0; k < 4; ++k) if (k < nr) {
            const uint2 g0 = *reinterpret_cast<const uint2*>(Xc + offB[k][0] + srcB);
            const uint2 g1 = *reinterpret_cast<const uint2*>(Xc + offB[k][1] + srcB);
            const uint2 g2 = *reinterpret_cast<const uint2*>(Xc + offB[k][2] + srcB);
            const f32x2 a01 = (unpk(g0.x) + unpk(g1.x)) + unpk(g2.x);
            const f32x2 a23 = (unpk(g0.y) + unpk(g1.y)) + unpk(g2.y);
            const f32x2 q01 = div3v(a01), q23 = div3v(a23);
            uint2 nv;
            nv.x = pkbf(q01.x, q01.y);
            nv.y = pkbf(q23.x, q23.y);
            *reinterpret_cast<uint2*>(Xc + r0b + ((k << 11) + dstB)) = nv;
            const f32x2 n01 = unpk(nv.x), n23 = unpk(nv.y);
            const f32x2 d01v = n01 - old01[k];
            const f32x2 d23v = n23 - old23[k];
            const u32 d01 = pkbf(d01v.x, d01v.y);
            const u32 d23 = pkbf(d23v.x, d23v.y);
            dacc += fabsf(bflo(d01));
            dacc += fabsf(bfhi(d01));
            dacc += fabsf(bflo(d23));
            dacc += fabsf(bfhi(d23));
            old01[k] = n01; old23[k] = n23;
        }
        #pragma unroll
        for (int off = 32; off > 0; off >>= 1) dacc += __shfl_down(dacc, off);
        if ((tid & 63) == 0) redL[s & 1][tid >> 6] = dacc;
        barrier_lds_only();
        if (tid == 0) {
            const float dtot = ((redL[s & 1][0] + redL[s & 1][1])
                                + redL[s & 1][2]) + redL[s & 1][3];
            partials[((size_t)(s - 1) * BS + b) * NSLAB + sl] = dtot;
        }
        if (s == 20 || s == 28 || s == 36 || s == 44 || s == 50) {
            char* slotC = reinterpret_cast<char*>(slots)
                        + (size_t)cpSlot * SLOTB;
            #pragma unroll
            for (int k = 0; k < 4; ++k) if (k < nr)
                *reinterpret_cast<uint2*>(slotC + rowByte[k]) =
                    *reinterpret_cast<const uint2*>(Xc + r0b + ((k << 11) + dstB));
            cpSlot ^= 1;
        }
        srcB = dstB;
    }
}

// ---------------------------------------------------------------------------
// findS: incremental (ctrl[3] = next unscanned s). EXACT decision math.
// ---------------------------------------------------------------------------
__global__ void findS_kernel(const float* __restrict__ partials,
                             int* __restrict__ ctrl, int smax) {
    if (ctrl[2] != 0) return;
    const int lane = threadIdx.x;
    const int sStart = (ctrl[3] > 1) ? ctrl[3] : 1;
    const float tol_bf = bf2f(f2bf(1e-5f));
    int S = -1;
    for (int s = sStart; s <= smax; ++s) {
        const float* p = partials + ((size_t)(s - 1) * BS + lane) * NSLAB;
        float t = 0.f;
        #pragma unroll
        for (int k = 0; k < NSLAB; ++k) t += p[k];
        const float lnorm = bf2f(f2bf(t / 261120.0f));
        if (__ballot(lnorm > tol_bf) == 0ULL) { S = s; break; }
    }
    if (S < 0 && smax == ITERS) S = ITERS;
    if (lane == 0) {
        if (S > 0) { ctrl[0] = S; ctrl[2] = 1; }
        else         ctrl[3] = smax + 1;
    }
}

// ---------------------------------------------------------------------------
// ident: identity block (rows 0..511, all trees) — row-contiguous, full BW.
// ---------------------------------------------------------------------------
__global__ __launch_bounds__(256) void ident_kernel(float* __restrict__ out) {
    const size_t nf4 = (size_t)BS * NTIPS * NTIPS / 4;   // 4,194,304 float4
    for (size_t i = (size_t)blockIdx.x * 256 + threadIdx.x; i < nf4;
         i += (size_t)gridDim.x * 256) {
        const u32 b   = (u32)(i >> 16);          // 65536 float4 per tree
        const u32 rem = (u32)(i & 65535u);
        const u32 r   = rem >> 7;                // 128 float4 per row
        const u32 c0  = (rem & 127u) << 2;
        float4 v;
        v.x = (r == c0 + 0) ? 1.f : 0.f;
        v.y = (r == c0 + 1) ? 1.f : 0.f;
        v.z = (r == c0 + 2) ? 1.f : 0.f;
        v.w = (r == c0 + 3) ? 1.f : 0.f;
        *reinterpret_cast<float4*>(out + (size_t)b * TOTAL * NTIPS
                                   + (size_t)r * NTIPS + c0) = v;
    }
}

// ---------------------------------------------------------------------------
// copyfinal (fallback only, slots in d_out): resolved slot -> ws verbatim.
// ---------------------------------------------------------------------------
__global__ __launch_bounds__(256) void copyfinal_kernel(
        const int* __restrict__ ctrl, const u16* __restrict__ slots,
        u16* __restrict__ dst) {
    int T, slot, fromX0;
    resolveS(ctrl[0], T, slot, fromX0);
    if (fromX0) return;
    const uint4* src = reinterpret_cast<const uint4*>(slots + (size_t)slot * XB);
    uint4* d = reinterpret_cast<uint4*>(dst);
    const size_t n = XB / 8;
    for (size_t i = (size_t)blockIdx.x * 256 + threadIdx.x; i < n;
         i += (size_t)gridDim.x * 256)
        d[i] = src[i];
}

// ---------------------------------------------------------------------------
// phaseCX: resume from resolved checkpoint, run T (<=2 common case) steps,
// write ONLY the X block (rows 512..1021) as fp32. R9-verbatim.
// ---------------------------------------------------------------------------
__global__ __launch_bounds__(256, 4) void phaseCX_kernel(
        const int* __restrict__ edge, const int* __restrict__ ctrl,
        const u16* __restrict__ s0, int ring, float* __restrict__ out) {
    __shared__ u16 X[BSTR2];

    int T, slot, fromX0;
    resolveS(ctrl[0], T, slot, fromX0);

    const int wg = blockIdx.x, b = wg >> 5, sl = wg & 31;   // 16-feat slab
    const int tid = threadIdx.x;
    const int rg = tid >> 2;                 // row group 0..63
    const int l  = tid & 3;
    const int lbyte = l << 3;
    const int nr = (rg < 62) ? 8 : 7;
    char* Xc = reinterpret_cast<char*>(X);
    const u32 r0b = (u32)(rg * 32 + lbyte);

    u32 offB[8][3];
    #pragma unroll
    for (int k = 0; k < 8; ++k) if (k < nr) {
        const int i = rg + (k << 6);
        const int* ep = edge + ((size_t)b * TOTAL + NTIPS + i) * 3;
        #pragma unroll
        for (int t = 0; t < 3; ++t) {
            const int e = ep[t];
            u32 off;
            if (e >= NTIPS)          off = (u32)((e - NTIPS) * ROWEL2);
            else if ((e >> 4) == sl) off = (u32)(ONE2 + (e & 15) * ROWEL2);
            else                     off = (u32)ZROW2;
            offB[k][t] = off * 2u + (u32)lbyte;
        }
    }

    if (fromX0) {
        for (int j = tid; j < XSEC2 / 2; j += 256)
            reinterpret_cast<u32*>(X)[j] = 0x3B003B00u;
    } else {
        // translate from 8-feat slab-major snapshot (R7/R9-proven)
        const char* src = reinterpret_cast<const char*>(s0)
                        + (ring ? (size_t)slot * SLOTB : (size_t)0);
        const u32 sb = (u32)(b * NSLAB + sl * 2 + (l >> 1)) * (u32)WGB
                     + (u32)((l & 1) << 3);
        #pragma unroll
        for (int k = 0; k < 8; ++k) if (k < nr) {
            const int r = rg + (k << 6);
            *reinterpret_cast<uint2*>(Xc + r0b + (k << 11)) =
                *reinterpret_cast<const uint2*>(src + sb + (u32)(r * 16));
        }
    }
    for (int j = tid; j < 17 * ROWEL2; j += 256) {
        const int row = j >> 4, col = j & 15;
        X[ONE2 + j] = (row == col) ? (u16)0x3F80 : (u16)0;
    }
    __syncthreads();

    for (int t = 1; t <= T; ++t) {
        uint2 nv[8];
        #pragma unroll
        for (int k = 0; k < 8; ++k) if (k < nr) {
            const uint2 g0 = *reinterpret_cast<const uint2*>(Xc + offB[k][0]);
            const uint2 g1 = *reinterpret_cast<const uint2*>(Xc + offB[k][1]);
            const uint2 g2 = *reinterpret_cast<const uint2*>(Xc + offB[k][2]);
            nv[k].x = stepND(g0.x, g1.x, g2.x);
            nv[k].y = stepND(g0.y, g1.y, g2.y);
        }
        __syncthreads();
        #pragma unroll
        for (int k = 0; k < 8; ++k) if (k < nr)
            *reinterpret_cast<uint2*>(Xc + r0b + (k << 11)) = nv[k];
        __syncthreads();
    }

    // X block only: WG owns feature cols [sl*16, sl*16+16) of tree b.
    float* xbase = out + (size_t)b * TOTAL * NTIPS
                 + (size_t)NTIPS * NTIPS + sl * 16;
    for (int j = tid; j < DIM * 4; j += 256) {
        const int r = j >> 2, c4 = (j & 3) << 2;
        const ushort4 a = *reinterpret_cast<const ushort4*>(&X[r * ROWEL2 + c4]);
        float4 v;
        v.x = bf2f(a.x); v.y = bf2f(a.y); v.z = bf2f(a.z); v.w = bf2f(a.w);
        *reinterpret_cast<float4*>(xbase + (size_t)r * NTIPS + c4) = v;
    }
}

extern "C" void kernel_launch(void* const* d_in, const int* in_sizes, int n_in,
                              void* d_out, int out_size, void* d_ws, size_t ws_size,
                              hipStream_t stream) {
    const int* edge = (const int*)d_in[1];       // (BS, TOTAL, 3) int32
    float* out = (float*)d_out;
    const size_t partB = NPART * sizeof(float);

    if (ws_size >= 2 * SLOTB + partB + 256) {
        // ---- primary: 2-slot ring in ws ----
        u16*   slots    = (u16*)d_ws;
        float* partials = (float*)((char*)d_ws + 2 * SLOTB);
        int*   ctrl     = (int*)((char*)partials + partB);
        hipMemsetAsync(ctrl, 0, 4 * sizeof(int), stream);
        ident_kernel<<<2048, 256, 0, stream>>>(out);
        live12_kernel<<<NWG, 256, 0, stream>>>(edge, partials, slots);
        findS_kernel<<<1, 64, 0, stream>>>(partials, ctrl, 12);
        tail_kernel<<<NWG, 256, 0, stream>>>(edge, partials, ctrl, slots);
        findS_kernel<<<1, 64, 0, stream>>>(partials, ctrl, 50);
        phaseCX_kernel<<<NWG2, 256, 0, stream>>>(edge, ctrl, slots, 1, out);
    } else {
        // ---- fallback: 2-slot ring in d_out; extract, then ident, then X ----
        u16*   slots    = (u16*)d_out;
        u16*   finalX   = (u16*)d_ws;
        float* partials = (float*)((char*)d_ws + SLOTB);
        int*   ctrl     = (int*)((char*)partials + partB);
        hipMemsetAsync(ctrl, 0, 4 * sizeof(int), stream);
        live12_kernel<<<NWG, 256, 0, stream>>>(edge, partials, slots);
        findS_kernel<<<1, 64, 0, stream>>>(partials, ctrl, 12);
        tail_kernel<<<NWG, 256, 0, stream>>>(edge, partials, ctrl, slots);
        findS_kernel<<<1, 64, 0, stream>>>(partials, ctrl, 50);
        copyfinal_kernel<<<2048, 256, 0, stream>>>(ctrl, slots, finalX);
        ident_kernel<<<2048, 256, 0, stream>>>(out);
        phaseCX_kernel<<<NWG2, 256, 0, stream>>>(edge, ctrl, finalX, 0, out);
    }
}

// Round 11
// 241.088 us; speedup vs baseline: 3.9383x; 1.0251x over previous
//
#include <hip/hip_runtime.h>

// ---- problem geometry ----
#define NTIPS 512
#define DIM   510                     // internal nodes = ntips - 2
#define TOTAL 1022
#define BS    64
#define ITERS 50

// ---- chunk config: 8-feat slabs (R4/R7/R9/R10-proven uint2 body), dbuf ----
#define NSLAB 64
#define NWG   (BS * NSLAB)            // 4096 workgroups
#define NPART ((size_t)ITERS * BS * NSLAB)
#define ROWEL 8                       // u16 per row-slab (16 B)
#define XSEC   (DIM * ROWEL)          // 4080 u16
#define ONEOFF XSEC                   // 8 one-hot const rows
#define ZROW   (XSEC + 8 * ROWEL)     // all-zero const row
#define BSTRIDE (XSEC + 9 * ROWEL)    // 4152 u16 per LDS buffer
#define BUFB   (BSTRIDE * 2)          // 8304 B per buffer (2 buffers = 16.6KB)
#define WGB    (DIM * ROWEL * 2)      // 8160 B per WG region in a slot
#define XB     ((size_t)BS * DIM * NTIPS)  // u16 per snapshot slot
#define SLOTB  (XB * 2)               // 33.4 MB per slot

// ---- phaseC config: 16-feat slabs, single-buffer ----
#define NSLAB2 32
#define NWG2   (BS * NSLAB2)          // 2048 workgroups
#define ROWEL2 16
#define XSEC2  (DIM * ROWEL2)         // 8160 u16
#define ONE2   XSEC2
#define ZROW2  (XSEC2 + 16 * ROWEL2)
#define BSTR2  (XSEC2 + 17 * ROWEL2)  // 8432 u16 = 16864 B

typedef unsigned short u16;
typedef unsigned int   u32;
typedef float f32x2 __attribute__((ext_vector_type(2)));

// bf16 RNE helpers (validated chain)
__device__ __forceinline__ u16 f2bf(float x) {
    u32 u = __float_as_uint(x);
    return (u16)((u + 0x7FFFu + ((u >> 16) & 1u)) >> 16);
}
__device__ __forceinline__ float bf2f(u16 h) { return __uint_as_float(((u32)h) << 16); }
__device__ __forceinline__ float bflo(u32 p) { return __uint_as_float(p << 16); }
__device__ __forceinline__ float bfhi(u32 p) { return __uint_as_float(p & 0xFFFF0000u); }
__device__ __forceinline__ f32x2 unpk(u32 p) {
    f32x2 r; r.x = bflo(p); r.y = bfhi(p); return r;
}

#if defined(__has_builtin)
#  if __has_builtin(__builtin_amdgcn_cvt_pk_bf16_f32)
#    define HAVE_PKBF 1
#  endif
#endif
#ifdef HAVE_PKBF
typedef __bf16 bf16x2 __attribute__((ext_vector_type(2)));
__device__ __forceinline__ u32 pkbf(float a, float b) {   // lo=a, hi=b, RNE
    bf16x2 r = __builtin_amdgcn_cvt_pk_bf16_f32(a, b);
    return __builtin_bit_cast(u32, r);
}
#else
__device__ __forceinline__ u32 pkbf(float a, float b) {
    return (u32)f2bf(a) | ((u32)f2bf(b) << 16);
}
#endif

// correctly-rounded f32 /3 (Markstein mul+2fma) — R2..R10-validated
__device__ __forceinline__ f32x2 div3v(f32x2 x) {
    const float C = 0x1.555556p-2f;               // RN(1/3)
    f32x2 q0, r, q;
    q0.x = x.x * C;             q0.y = x.y * C;
    r.x = fmaf(-3.f, q0.x, x.x); r.y = fmaf(-3.f, q0.y, x.y);
    q.x = fmaf(r.x, C, q0.x);    q.y = fmaf(r.y, C, q0.y);
    return q;
}
// no-delta packed-pair step (phaseC)
__device__ __forceinline__ u32 stepND(u32 a0, u32 a1, u32 a2) {
    const f32x2 a = (unpk(a0) + unpk(a1)) + unpk(a2);
    const f32x2 q = div3v(a);
    return pkbf(q.x, q.y);
}

// LDS-only barrier (R3..R10-validated): no vmcnt drain
__device__ __forceinline__ void barrier_lds_only() {
    __builtin_amdgcn_sched_barrier(0);
    asm volatile("s_waitcnt lgkmcnt(0)" ::: "memory");
    __builtin_amdgcn_s_barrier();
    __builtin_amdgcn_sched_barrier(0);
}

// checkpoints: step {9,12,20,28,36,44,50} -> slot {1,0,1,0,1,0,1} (R10)
__device__ __forceinline__ void resolveS(int S, int& T, int& slot, int& fromX0) {
    const int cps[7] = {9, 12, 20, 28, 36, 44, 50};
    fromX0 = 0; T = S; slot = 0;
    int cp = 0;
    #pragma unroll
    for (int i = 0; i < 7; ++i)
        if (cps[i] <= S) { cp = cps[i]; slot = (i + 1) & 1; }
    if (cp == 0) fromX0 = 1;
    else         T = S - cp;
}

// gather offsets for 8-feat slabs (BYTE units, buffer-relative) — R4-proven
__device__ __forceinline__ void make_offsets8(const int* __restrict__ edge,
        int b, int sl, int rg, int lbyte, int nr, u32 offB[4][3]) {
    #pragma unroll
    for (int k = 0; k < 4; ++k) if (k < nr) {
        const int i = rg + 128 * k;
        const int* ep = edge + ((size_t)b * TOTAL + NTIPS + i) * 3;
        #pragma unroll
        for (int t = 0; t < 3; ++t) {
            const int e = ep[t];
            u32 off;
            if (e >= NTIPS)          off = (u32)((e - NTIPS) * ROWEL);
            else if ((e >> 3) == sl) off = (u32)(ONEOFF + (e & 7) * ROWEL);
            else                     off = (u32)ZROW;
            offB[k][t] = off * 2u + (u32)lbyte;
        }
    }
}

__device__ __forceinline__ void init_const_rows8(u16* X, int tid) {
    for (int j = tid; j < 9 * ROWEL; j += 256) {
        const int row = j >> 3, col = j & 7;
        const u16 v = (row == col) ? (u16)0x3F80 : (u16)0;  // row 8 = zeros
        X[ONEOFF + j] = v;
        X[BSTRIDE + ONEOFF + j] = v;
    }
}

// ---------------------------------------------------------------------------
// live12: steps 1..12 in ONE launch (R10-proven). Additions this round:
//  * doIdent: write the fp32 identity block (rows 0..511) — each WG owns a
//    contiguous 16 KB stripe (rows sl*8..sl*8+7 of tree b), 4 float4/thread,
//    issued before LDS init; fire-and-forget under the VALU-bound loop.
//  * WG0/tid0 clears ctrl (replaces host memset; visible via kernel boundary).
// Mid checkpoint step 9 -> slot 1, end checkpoint step 12 -> slot 0.
// ---------------------------------------------------------------------------
__global__ __launch_bounds__(256, 8) void live12_kernel(
        const int* __restrict__ edge, float* __restrict__ partials,
        int* __restrict__ ctrl, u16* __restrict__ slots,
        float* __restrict__ out, int doIdent) {
    __shared__ u16 X[2 * BSTRIDE];
    __shared__ float redL[2][4];

    const int wg = blockIdx.x, b = wg >> 6, sl = wg & 63;
    const int tid = threadIdx.x, rg = tid >> 1;
    const int lbyte = (tid & 1) << 3;
    const int nr = (rg < 126) ? 4 : 3;
    char* Xc = reinterpret_cast<char*>(X);
    const u32 r0b = (u32)(rg * 16 + lbyte);

    if (wg == 0 && tid == 0) {               // ctrl clear (was host memset)
        ctrl[0] = 0; ctrl[1] = 0; ctrl[2] = 0; ctrl[3] = 0;
    }
    if (doIdent) {                           // identity stripe: rows sl*8..+7
        const int r = (sl << 3) + (tid >> 5);
        const int c0 = (tid & 31) << 4;      // 16 floats per thread
        float* drow = out + ((size_t)b * TOTAL + r) * NTIPS + c0;
        #pragma unroll
        for (int m = 0; m < 4; ++m) {
            const int cb = c0 + (m << 2);
            float4 v;
            v.x = (r == cb + 0) ? 1.f : 0.f;
            v.y = (r == cb + 1) ? 1.f : 0.f;
            v.z = (r == cb + 2) ? 1.f : 0.f;
            v.w = (r == cb + 3) ? 1.f : 0.f;
            *reinterpret_cast<float4*>(drow + (m << 2)) = v;
        }
    }

    u32 offB[4][3];
    make_offsets8(edge, b, sl, rg, lbyte, nr, offB);

    u32 rowByte[4];
    #pragma unroll
    for (int k = 0; k < 4; ++k)
        rowByte[k] = (u32)wg * (u32)WGB + (u32)((rg + 128 * k) * 16) + (u32)lbyte;

    for (int j = tid; j < XSEC / 2; j += 256)
        reinterpret_cast<u32*>(X)[j] = 0x3B003B00u;       // X0 = bf16(1/512)
    init_const_rows8(X, tid);

    f32x2 old01[4], old23[4];
    #pragma unroll
    for (int k = 0; k < 4; ++k) if (k < nr) {
        const uint2 ov = *reinterpret_cast<const uint2*>(Xc + r0b + (k << 11));
        old01[k] = unpk(ov.x); old23[k] = unpk(ov.y);
    }
    __syncthreads();

    char* slot1C = reinterpret_cast<char*>(slots) + SLOTB;   // step-9 cp
    #pragma unroll
    for (int u = 0; u < 12; ++u) {
        const int s = 1 + u;
        const int srcB = (u & 1) ? BUFB : 0;
        const int dstB = ((u + 1) & 1) ? BUFB : 0;
        float dacc = 0.f;
        #pragma unroll
        for (int k = 0; k < 4; ++k) if (k < nr) {
            const uint2 g0 = *reinterpret_cast<const uint2*>(Xc + offB[k][0] + srcB);
            const uint2 g1 = *reinterpret_cast<const uint2*>(Xc + offB[k][1] + srcB);
            const uint2 g2 = *reinterpret_cast<const uint2*>(Xc + offB[k][2] + srcB);
            const f32x2 a01 = (unpk(g0.x) + unpk(g1.x)) + unpk(g2.x);
            const f32x2 a23 = (unpk(g0.y) + unpk(g1.y)) + unpk(g2.y);
            const f32x2 q01 = div3v(a01), q23 = div3v(a23);
            uint2 nv;
            nv.x = pkbf(q01.x, q01.y);
            nv.y = pkbf(q23.x, q23.y);
            *reinterpret_cast<uint2*>(Xc + r0b + ((k << 11) + dstB)) = nv;
            if (u == 8)                              // step 9 checkpoint
                *reinterpret_cast<uint2*>(slot1C + rowByte[k]) = nv;
            const f32x2 n01 = unpk(nv.x), n23 = unpk(nv.y);
            const f32x2 d01v = n01 - old01[k];
            const f32x2 d23v = n23 - old23[k];
            const u32 d01 = pkbf(d01v.x, d01v.y);
            const u32 d23 = pkbf(d23v.x, d23v.y);
            dacc += fabsf(bflo(d01));
            dacc += fabsf(bfhi(d01));
            dacc += fabsf(bflo(d23));
            dacc += fabsf(bfhi(d23));
            old01[k] = n01; old23[k] = n23;
        }
        #pragma unroll
        for (int off = 32; off > 0; off >>= 1) dacc += __shfl_down(dacc, off);
        if ((tid & 63) == 0) redL[u & 1][tid >> 6] = dacc;
        barrier_lds_only();
        if (tid == 0) {
            const float dtot = ((redL[u & 1][0] + redL[u & 1][1])
                                + redL[u & 1][2]) + redL[u & 1][3];
            partials[((size_t)(s - 1) * BS + b) * NSLAB + sl] = dtot;
        }
    }

    // end checkpoint: step 12 (buffer 0) -> slot 0
    char* slot0C = reinterpret_cast<char*>(slots);
    #pragma unroll
    for (int k = 0; k < 4; ++k) if (k < nr)
        *reinterpret_cast<uint2*>(slot0C + rowByte[k]) =
            *reinterpret_cast<const uint2*>(Xc + r0b + (k << 11));
}

// ---------------------------------------------------------------------------
// tail: steps 13..50 in ONE gated launch (R10-verbatim). Checkpoints
// 20/28/36/44/50 alternating slots starting 1. Reloads cp12 (slot 0).
// ---------------------------------------------------------------------------
__global__ __launch_bounds__(256, 8) void tail_kernel(
        const int* __restrict__ edge, float* __restrict__ partials,
        const int* __restrict__ ctrl, u16* __restrict__ slots) {
    if (ctrl[2] != 0) return;                    // common case: skip

    __shared__ u16 X[2 * BSTRIDE];
    __shared__ float redL[2][4];

    const int wg = blockIdx.x, b = wg >> 6, sl = wg & 63;
    const int tid = threadIdx.x, rg = tid >> 1;
    const int lbyte = (tid & 1) << 3;
    const int nr = (rg < 126) ? 4 : 3;
    char* Xc = reinterpret_cast<char*>(X);
    const u32 r0b = (u32)(rg * 16 + lbyte);

    u32 offB[4][3];
    make_offsets8(edge, b, sl, rg, lbyte, nr, offB);

    u32 rowByte[4];
    #pragma unroll
    for (int k = 0; k < 4; ++k)
        rowByte[k] = (u32)wg * (u32)WGB + (u32)((rg + 128 * k) * 16) + (u32)lbyte;

    {   // reload checkpoint step 12 (slot 0)
        const char* src0 = reinterpret_cast<const char*>(slots);
        #pragma unroll
        for (int k = 0; k < 4; ++k) if (k < nr)
            *reinterpret_cast<uint2*>(Xc + r0b + (k << 11)) =
                *reinterpret_cast<const uint2*>(src0 + rowByte[k]);
    }
    init_const_rows8(X, tid);

    f32x2 old01[4], old23[4];
    #pragma unroll
    for (int k = 0; k < 4; ++k) if (k < nr) {
        const uint2 ov = *reinterpret_cast<const uint2*>(Xc + r0b + (k << 11));
        old01[k] = unpk(ov.x); old23[k] = unpk(ov.y);
    }
    __syncthreads();

    u32 srcB = 0;
    int cpSlot = 1;
    for (int s = 13; s <= 50; ++s) {
        const u32 dstB = srcB ^ (u32)BUFB;
        float dacc = 0.f;
        #pragma unroll
        for (int k = 0; k < 4; ++k) if (k < nr) {
            const uint2 g0 = *reinterpret_cast<const uint2*>(Xc + offB[k][0] + srcB);
            const uint2 g1 = *reinterpret_cast<const uint2*>(Xc + offB[k][1] + srcB);
            const uint2 g2 = *reinterpret_cast<const uint2*>(Xc + offB[k][2] + srcB);
            const f32x2 a01 = (unpk(g0.x) + unpk(g1.x)) + unpk(g2.x);
            const f32x2 a23 = (unpk(g0.y) + unpk(g1.y)) + unpk(g2.y);
            const f32x2 q01 = div3v(a01), q23 = div3v(a23);
            uint2 nv;
            nv.x = pkbf(q01.x, q01.y);
            nv.y = pkbf(q23.x, q23.y);
            *reinterpret_cast<uint2*>(Xc + r0b + ((k << 11) + dstB)) = nv;
            const f32x2 n01 = unpk(nv.x), n23 = unpk(nv.y);
            const f32x2 d01v = n01 - old01[k];
            const f32x2 d23v = n23 - old23[k];
            const u32 d01 = pkbf(d01v.x, d01v.y);
            const u32 d23 = pkbf(d23v.x, d23v.y);
            dacc += fabsf(bflo(d01));
            dacc += fabsf(bfhi(d01));
            dacc += fabsf(bflo(d23));
            dacc += fabsf(bfhi(d23));
            old01[k] = n01; old23[k] = n23;
        }
        #pragma unroll
        for (int off = 32; off > 0; off >>= 1) dacc += __shfl_down(dacc, off);
        if ((tid & 63) == 0) redL[s & 1][tid >> 6] = dacc;
        barrier_lds_only();
        if (tid == 0) {
            const float dtot = ((redL[s & 1][0] + redL[s & 1][1])
                                + redL[s & 1][2]) + redL[s & 1][3];
            partials[((size_t)(s - 1) * BS + b) * NSLAB + sl] = dtot;
        }
        if (s == 20 || s == 28 || s == 36 || s == 44 || s == 50) {
            char* slotC = reinterpret_cast<char*>(slots)
                        + (size_t)cpSlot * SLOTB;
            #pragma unroll
            for (int k = 0; k < 4; ++k) if (k < nr)
                *reinterpret_cast<uint2*>(slotC + rowByte[k]) =
                    *reinterpret_cast<const uint2*>(Xc + r0b + ((k << 11) + dstB));
            cpSlot ^= 1;
        }
        srcB = dstB;
    }
}

// ---------------------------------------------------------------------------
// findS: incremental (ctrl[3] = next unscanned s). EXACT decision math.
// ---------------------------------------------------------------------------
__global__ void findS_kernel(const float* __restrict__ partials,
                             int* __restrict__ ctrl, int smax) {
    if (ctrl[2] != 0) return;
    const int lane = threadIdx.x;
    const int sStart = (ctrl[3] > 1) ? ctrl[3] : 1;
    const float tol_bf = bf2f(f2bf(1e-5f));
    int S = -1;
    for (int s = sStart; s <= smax; ++s) {
        const float* p = partials + ((size_t)(s - 1) * BS + lane) * NSLAB;
        float t = 0.f;
        #pragma unroll
        for (int k = 0; k < NSLAB; ++k) t += p[k];
        const float lnorm = bf2f(f2bf(t / 261120.0f));
        if (__ballot(lnorm > tol_bf) == 0ULL) { S = s; break; }
    }
    if (S < 0 && smax == ITERS) S = ITERS;
    if (lane == 0) {
        if (S > 0) { ctrl[0] = S; ctrl[2] = 1; }
        else         ctrl[3] = smax + 1;
    }
}

// ---------------------------------------------------------------------------
// ident (fallback only): identity block, row-contiguous full-BW writer.
// ---------------------------------------------------------------------------
__global__ __launch_bounds__(256) void ident_kernel(float* __restrict__ out) {
    const size_t nf4 = (size_t)BS * NTIPS * NTIPS / 4;   // 4,194,304 float4
    for (size_t i = (size_t)blockIdx.x * 256 + threadIdx.x; i < nf4;
         i += (size_t)gridDim.x * 256) {
        const u32 b   = (u32)(i >> 16);          // 65536 float4 per tree
        const u32 rem = (u32)(i & 65535u);
        const u32 r   = rem >> 7;                // 128 float4 per row
        const u32 c0  = (rem & 127u) << 2;
        float4 v;
        v.x = (r == c0 + 0) ? 1.f : 0.f;
        v.y = (r == c0 + 1) ? 1.f : 0.f;
        v.z = (r == c0 + 2) ? 1.f : 0.f;
        v.w = (r == c0 + 3) ? 1.f : 0.f;
        *reinterpret_cast<float4*>(out + (size_t)b * TOTAL * NTIPS
                                   + (size_t)r * NTIPS + c0) = v;
    }
}

// ---------------------------------------------------------------------------
// copyfinal (fallback only, slots in d_out): resolved slot -> ws verbatim.
// ---------------------------------------------------------------------------
__global__ __launch_bounds__(256) void copyfinal_kernel(
        const int* __restrict__ ctrl, const u16* __restrict__ slots,
        u16* __restrict__ dst) {
    int T, slot, fromX0;
    resolveS(ctrl[0], T, slot, fromX0);
    if (fromX0) return;
    const uint4* src = reinterpret_cast<const uint4*>(slots + (size_t)slot * XB);
    uint4* d = reinterpret_cast<uint4*>(dst);
    const size_t n = XB / 8;
    for (size_t i = (size_t)blockIdx.x * 256 + threadIdx.x; i < n;
         i += (size_t)gridDim.x * 256)
        d[i] = src[i];
}

// ---------------------------------------------------------------------------
// phaseCX: resume from resolved checkpoint, run T (<=3) steps, write the
// X block (rows 512..1021) as fp32. Self-resolves S via the EXACT findS
// scan when ctrl[2]==0 (rare S>12 path; partials visible via kernel
// boundary after tail). R10-verbatim translation + step body.
// ---------------------------------------------------------------------------
__global__ __launch_bounds__(256, 4) void phaseCX_kernel(
        const int* __restrict__ edge, const float* __restrict__ partials,
        const int* __restrict__ ctrl, const u16* __restrict__ s0, int ring,
        float* __restrict__ out) {
    __shared__ u16 X[BSTR2];
    __shared__ int sS;

    const int wg = blockIdx.x, b = wg >> 5, sl = wg & 31;   // 16-feat slab
    const int tid = threadIdx.x;

    // ---- resolve S (common: ctrl; rare: in-kernel findS scan) ----
    const int found = ctrl[2];
    if (found != 0) {
        if (tid == 0) sS = ctrl[0];
    } else if (tid < 64) {                   // wave 0 = EXACT findS math
        const int sStart = (ctrl[3] > 1) ? ctrl[3] : 1;
        const float tol_bf = bf2f(f2bf(1e-5f));
        int S = -1;
        for (int s = sStart; s <= ITERS; ++s) {
            const float* p = partials + ((size_t)(s - 1) * BS + tid) * NSLAB;
            float t = 0.f;
            #pragma unroll
            for (int k = 0; k < NSLAB; ++k) t += p[k];
            const float lnorm = bf2f(f2bf(t / 261120.0f));
            if (__ballot(lnorm > tol_bf) == 0ULL) { S = s; break; }
        }
        if (S < 0) S = ITERS;                // cap at MAX_ITERS
        if (tid == 0) sS = S;
    }
    __syncthreads();
    int T, slot, fromX0;
    resolveS(sS, T, slot, fromX0);

    const int rg = tid >> 2;                 // row group 0..63
    const int l  = tid & 3;
    const int lbyte = l << 3;
    const int nr = (rg < 62) ? 8 : 7;
    char* Xc = reinterpret_cast<char*>(X);
    const u32 r0b = (u32)(rg * 32 + lbyte);

    u32 offB[8][3];
    #pragma unroll
    for (int k = 0; k < 8; ++k) if (k < nr) {
        const int i = rg + (k << 6);
        const int* ep = edge + ((size_t)b * TOTAL + NTIPS + i) * 3;
        #pragma unroll
        for (int t = 0; t < 3; ++t) {
            const int e = ep[t];
            u32 off;
            if (e >= NTIPS)          off = (u32)((e - NTIPS) * ROWEL2);
            else if ((e >> 4) == sl) off = (u32)(ONE2 + (e & 15) * ROWEL2);
            else                     off = (u32)ZROW2;
            offB[k][t] = off * 2u + (u32)lbyte;
        }
    }

    if (fromX0) {
        for (int j = tid; j < XSEC2 / 2; j += 256)
            reinterpret_cast<u32*>(X)[j] = 0x3B003B00u;
    } else {
        // translate from 8-feat slab-major snapshot (R7..R10-proven)
        const char* src = reinterpret_cast<const char*>(s0)
                        + (ring ? (size_t)slot * SLOTB : (size_t)0);
        const u32 sb = (u32)(b * NSLAB + sl * 2 + (l >> 1)) * (u32)WGB
                     + (u32)((l & 1) << 3);
        #pragma unroll
        for (int k = 0; k < 8; ++k) if (k < nr) {
            const int r = rg + (k << 6);
            *reinterpret_cast<uint2*>(Xc + r0b + (k << 11)) =
                *reinterpret_cast<const uint2*>(src + sb + (u32)(r * 16));
        }
    }
    for (int j = tid; j < 17 * ROWEL2; j += 256) {
        const int row = j >> 4, col = j & 15;
        X[ONE2 + j] = (row == col) ? (u16)0x3F80 : (u16)0;
    }
    __syncthreads();

    for (int t = 1; t <= T; ++t) {
        uint2 nv[8];
        #pragma unroll
        for (int k = 0; k < 8; ++k) if (k < nr) {
            const uint2 g0 = *reinterpret_cast<const uint2*>(Xc + offB[k][0]);
            const uint2 g1 = *reinterpret_cast<const uint2*>(Xc + offB[k][1]);
            const uint2 g2 = *reinterpret_cast<const uint2*>(Xc + offB[k][2]);
            nv[k].x = stepND(g0.x, g1.x, g2.x);
            nv[k].y = stepND(g0.y, g1.y, g2.y);
        }
        __syncthreads();
        #pragma unroll
        for (int k = 0; k < 8; ++k) if (k < nr)
            *reinterpret_cast<uint2*>(Xc + r0b + (k << 11)) = nv[k];
        __syncthreads();
    }

    // X block: WG owns feature cols [sl*16, sl*16+16) of tree b.
    float* xbase = out + (size_t)b * TOTAL * NTIPS
                 + (size_t)NTIPS * NTIPS + sl * 16;
    for (int j = tid; j < DIM * 4; j += 256) {
        const int r = j >> 2, c4 = (j & 3) << 2;
        const ushort4 a = *reinterpret_cast<const ushort4*>(&X[r * ROWEL2 + c4]);
        float4 v;
        v.x = bf2f(a.x); v.y = bf2f(a.y); v.z = bf2f(a.z); v.w = bf2f(a.w);
        *reinterpret_cast<float4*>(xbase + (size_t)r * NTIPS + c4) = v;
    }
}

extern "C" void kernel_launch(void* const* d_in, const int* in_sizes, int n_in,
                              void* d_out, int out_size, void* d_ws, size_t ws_size,
                              hipStream_t stream) {
    const int* edge = (const int*)d_in[1];       // (BS, TOTAL, 3) int32
    float* out = (float*)d_out;
    const size_t partB = NPART * sizeof(float);

    if (ws_size >= 2 * SLOTB + partB + 256) {
        // ---- primary: 2-slot ring in ws; 4 dispatches ----
        u16*   slots    = (u16*)d_ws;
        float* partials = (float*)((char*)d_ws + 2 * SLOTB);
        int*   ctrl     = (int*)((char*)partials + partB);
        live12_kernel<<<NWG, 256, 0, stream>>>(edge, partials, ctrl, slots,
                                               out, 1);
        findS_kernel<<<1, 64, 0, stream>>>(partials, ctrl, 12);
        tail_kernel<<<NWG, 256, 0, stream>>>(edge, partials, ctrl, slots);
        phaseCX_kernel<<<NWG2, 256, 0, stream>>>(edge, partials, ctrl,
                                                 slots, 1, out);
    } else {
        // ---- fallback: 2-slot ring in d_out; extract, then ident, then X ----
        u16*   slots    = (u16*)d_out;
        u16*   finalX   = (u16*)d_ws;
        float* partials = (float*)((char*)d_ws + SLOTB);
        int*   ctrl     = (int*)((char*)partials + partB);
        live12_kernel<<<NWG, 256, 0, stream>>>(edge, partials, ctrl, slots,
                                               nullptr, 0);
        findS_kernel<<<1, 64, 0, stream>>>(partials, ctrl, 12);
        tail_kernel<<<NWG, 256, 0, stream>>>(edge, partials, ctrl, slots);
        findS_kernel<<<1, 64, 0, stream>>>(partials, ctrl, 50);
        copyfinal_kernel<<<2048, 256, 0, stream>>>(ctrl, slots, finalX);
        ident_kernel<<<2048, 256, 0, stream>>>(out);
        phaseCX_kernel<<<NWG2, 256, 0, stream>>>(edge, partials, ctrl,
                                                 finalX, 0, out);
    }
}